// Round 3
// baseline (5395.724 us; speedup 1.0000x reference)
//
#include <hip/hip_runtime.h>
#include <math.h>

// Problem constants (from reference)
#define DIMS   1024
#define NHEAD  16
#define HD     64
#define WIN    512
#define CTX    4096
#define NBATCH 4
#define NROWS  (NBATCH*CTX)        // 16384 total sequence rows
#define NUNITS (NROWS*NHEAD)       // 262144 (row,head) units
#define LNEPS  1e-5f
#define FIXSCALE 16777216.0        // 2^24 fixed-point for deterministic diff

__device__ __forceinline__ float4 ld4(const float* p) { return *reinterpret_cast<const float4*>(p); }
__device__ __forceinline__ void st4(float* p, float4 v) { *reinterpret_cast<float4*>(p) = v; }

__device__ __forceinline__ float wave_sum64(float v) {
#pragma unroll
    for (int off = 32; off; off >>= 1) v += __shfl_xor(v, off, 64);
    return v;
}
// reduce across the 16 lanes sharing the same tm (tid = tm*16+tn)
__device__ __forceinline__ float grp16_sum(float v) {
    v += __shfl_xor(v, 1, 64);
    v += __shfl_xor(v, 2, 64);
    v += __shfl_xor(v, 4, 64);
    v += __shfl_xor(v, 8, 64);
    return v;
}
__device__ __forceinline__ float grp16_max(float v) {
    v = fmaxf(v, __shfl_xor(v, 1, 64));
    v = fmaxf(v, __shfl_xor(v, 2, 64));
    v = fmaxf(v, __shfl_xor(v, 4, 64));
    v = fmaxf(v, __shfl_xor(v, 8, 64));
    return v;
}

// -------- LayerNorm over D=1024 (row-wise), out = (x-m)*rsqrt(v+eps)*w --------
__global__ __launch_bounds__(256)
void ln1024_kernel(const float* __restrict__ x, const float* __restrict__ w,
                   float* __restrict__ outp) {
    int r = blockIdx.x;
    int tid = threadIdx.x;
    const float* xr = x + (size_t)r * DIMS;
    float4 v = ld4(xr + (tid << 2));
    __shared__ float red[8];
    float s = wave_sum64(v.x + v.y + v.z + v.w);
    int wv = tid >> 6, lane = tid & 63;
    if (lane == 0) red[wv] = s;
    __syncthreads();
    float mean = (red[0] + red[1] + red[2] + red[3]) * (1.0f / DIMS);
    float dx = v.x - mean, dy = v.y - mean, dz = v.z - mean, dw = v.w - mean;
    float ss = wave_sum64(dx*dx + dy*dy + dz*dz + dw*dw);
    if (lane == 0) red[4 + wv] = ss;
    __syncthreads();
    float inv = rsqrtf((red[4] + red[5] + red[6] + red[7]) * (1.0f / DIMS) + LNEPS);
    float4 wv4 = ld4(w + (tid << 2));
    st4(outp + (size_t)r * DIMS + (tid << 2),
        make_float4(dx * inv * wv4.x, dy * inv * wv4.y, dz * inv * wv4.z, dw * inv * wv4.w));
}

// -------- fp32 GEMM  C[m,n] = alpha*(sum_k A[m,k]*W[n,k] + bias[n]) ----------
// A row-major [M,K], W row-major [N,K] ("NT": both K-contiguous). 128x128x16 tile.
__global__ __launch_bounds__(256)
void gemm_nt_kernel(const float* __restrict__ A, const float* __restrict__ W,
                    const float* __restrict__ bias, float* __restrict__ Cm,
                    int M, int N, int K, float alpha, int has_bias) {
    __shared__ float As[16][132];
    __shared__ float Bs[16][132];
    int bm = blockIdx.x, bn = blockIdx.y;
    int tid = threadIdx.x;
    int tm = tid >> 4, tn = tid & 15;
    int lr = tid >> 2;
    int lc = (tid & 3) << 2;
    const float* Ag = A + (size_t)bm * 128 * K;
    const float* Wg = W + (size_t)bn * 128 * K;
    float acc[8][8] = {};
    for (int k0 = 0; k0 < K; k0 += 16) {
        float4 a0 = ld4(Ag + (size_t)lr * K + k0 + lc);
        float4 a1 = ld4(Ag + (size_t)(lr + 64) * K + k0 + lc);
        float4 b0 = ld4(Wg + (size_t)lr * K + k0 + lc);
        float4 b1 = ld4(Wg + (size_t)(lr + 64) * K + k0 + lc);
        __syncthreads();
        As[lc+0][lr] = a0.x; As[lc+1][lr] = a0.y; As[lc+2][lr] = a0.z; As[lc+3][lr] = a0.w;
        As[lc+0][lr+64] = a1.x; As[lc+1][lr+64] = a1.y; As[lc+2][lr+64] = a1.z; As[lc+3][lr+64] = a1.w;
        Bs[lc+0][lr] = b0.x; Bs[lc+1][lr] = b0.y; Bs[lc+2][lr] = b0.z; Bs[lc+3][lr] = b0.w;
        Bs[lc+0][lr+64] = b1.x; Bs[lc+1][lr+64] = b1.y; Bs[lc+2][lr+64] = b1.z; Bs[lc+3][lr+64] = b1.w;
        __syncthreads();
#pragma unroll
        for (int kk = 0; kk < 16; ++kk) {
            float a[8], bv[8];
            *reinterpret_cast<float4*>(&a[0])  = ld4(&As[kk][tm << 3]);
            *reinterpret_cast<float4*>(&a[4])  = ld4(&As[kk][(tm << 3) + 4]);
            *reinterpret_cast<float4*>(&bv[0]) = ld4(&Bs[kk][tn << 3]);
            *reinterpret_cast<float4*>(&bv[4]) = ld4(&Bs[kk][(tn << 3) + 4]);
#pragma unroll
            for (int i = 0; i < 8; ++i)
#pragma unroll
                for (int j = 0; j < 8; ++j)
                    acc[i][j] = fmaf(a[i], bv[j], acc[i][j]);
        }
    }
    int m0 = bm * 128 + (tm << 3);
    int n0 = bn * 128 + (tn << 3);
    float bb[8];
#pragma unroll
    for (int j = 0; j < 8; ++j) bb[j] = has_bias ? bias[n0 + j] : 0.0f;
#pragma unroll
    for (int i = 0; i < 8; ++i) {
        float o[8];
#pragma unroll
        for (int j = 0; j < 8; ++j) o[j] = alpha * (acc[i][j] + bb[j]);
        st4(Cm + (size_t)(m0 + i) * N + n0,     make_float4(o[0], o[1], o[2], o[3]));
        st4(Cm + (size_t)(m0 + i) * N + n0 + 4, make_float4(o[4], o[5], o[6], o[7]));
    }
}

// -------- per-(row,head) LayerNorm over d=64, in place on q and k ------------
__global__ __launch_bounds__(256)
void headln_kernel(float* __restrict__ q, float* __restrict__ k,
                   const float* __restrict__ lnw) {
    int gw = (blockIdx.x << 2) + (threadIdx.x >> 6);   // global wave = unit index
    int lane = threadIdx.x & 63;
    size_t idx = ((size_t)gw << 6) + lane;
    float wgt = lnw[lane];
    {
        float v = q[idx];
        float mean = wave_sum64(v) * (1.0f / 64.0f);
        float d = v - mean;
        float var = wave_sum64(d * d) * (1.0f / 64.0f);
        q[idx] = d * rsqrtf(var + LNEPS) * wgt;
    }
    {
        float v = k[idx];
        float mean = wave_sum64(v) * (1.0f / 64.0f);
        float d = v - mean;
        float var = wave_sum64(d * d) * (1.0f / 64.0f);
        k[idx] = d * rsqrtf(var + LNEPS) * wgt;
    }
}

// -------- 64x64 per-head projection: out[u,:] = maybeLN(in[u,:] @ W^T + Wb) --
template<int DO_LN>
__global__ __launch_bounds__(256)
void proj64_kernel(const float* __restrict__ inp, const float* __restrict__ W,
                   const float* __restrict__ Wb, const float* __restrict__ lnw,
                   float* __restrict__ outp) {
    int u0 = blockIdx.x << 6;
    __shared__ float As[64][68];   // As[i][m]   (input transposed)
    __shared__ float Bs[64][68];   // Bs[i][n] = W[n][i]
    int tid = threadIdx.x;
    for (int e = tid; e < 4096; e += 256) Bs[e & 63][e >> 6] = W[e];
    for (int e = tid; e < 1024; e += 256) {
        int row = e >> 4;
        int col = (e & 15) << 2;
        float4 v = ld4(inp + ((size_t)(u0 + row) << 6) + col);
        As[col + 0][row] = v.x; As[col + 1][row] = v.y;
        As[col + 2][row] = v.z; As[col + 3][row] = v.w;
    }
    __syncthreads();
    int tm = tid >> 4, tn = tid & 15;
    float acc[4][4] = {};
#pragma unroll
    for (int k = 0; k < 64; ++k) {
        float4 av = ld4(&As[k][tm << 2]);
        float4 bv = ld4(&Bs[k][tn << 2]);
        float aa[4] = {av.x, av.y, av.z, av.w};
        float bb[4] = {bv.x, bv.y, bv.z, bv.w};
#pragma unroll
        for (int mm = 0; mm < 4; ++mm)
#pragma unroll
            for (int nn = 0; nn < 4; ++nn)
                acc[mm][nn] = fmaf(aa[mm], bb[nn], acc[mm][nn]);
    }
    float bb4[4] = {Wb[(tn << 2) + 0], Wb[(tn << 2) + 1], Wb[(tn << 2) + 2], Wb[(tn << 2) + 3]};
    float lw4[4] = {0, 0, 0, 0};
    if (DO_LN) {
        lw4[0] = lnw[(tn << 2) + 0]; lw4[1] = lnw[(tn << 2) + 1];
        lw4[2] = lnw[(tn << 2) + 2]; lw4[3] = lnw[(tn << 2) + 3];
    }
#pragma unroll
    for (int mm = 0; mm < 4; ++mm) {
        float o0 = acc[mm][0] + bb4[0], o1 = acc[mm][1] + bb4[1];
        float o2 = acc[mm][2] + bb4[2], o3 = acc[mm][3] + bb4[3];
        if (DO_LN) {
            float mean = grp16_sum(o0 + o1 + o2 + o3) * (1.0f / 64.0f);
            float d0 = o0 - mean, d1 = o1 - mean, d2 = o2 - mean, d3 = o3 - mean;
            float var = grp16_sum(d0*d0 + d1*d1 + d2*d2 + d3*d3) * (1.0f / 64.0f);
            float inv = rsqrtf(var + LNEPS);
            o0 = d0 * inv * lw4[0]; o1 = d1 * inv * lw4[1];
            o2 = d2 * inv * lw4[2]; o3 = d3 * inv * lw4[3];
        }
        st4(outp + ((size_t)(u0 + (tm << 2) + mm) << 6) + (tn << 2),
            make_float4(o0, o1, o2, o3));
    }
}

// -------- fused attention: qp = LN(qacc @ lqw^T + lqb) computed in-block -----
// blockIdx.x = unit*8 + qtile. Reads qacc/kp/vp; writes o to o_io (own region).
// DIFF: accumulate per-window sum|o_new - o_io_prev| into u64 fixed-point.
// USE_CONV: skip block entirely if its window converged (o_io keeps o1).
template<int DIFF, int USE_CONV>
__global__ __launch_bounds__(256)
void attn_fused_kernel(const float* __restrict__ qacc, const float* __restrict__ kp,
                       const float* __restrict__ vp, float* __restrict__ o_io,
                       const float* __restrict__ lqw, const float* __restrict__ lqb,
                       const float* __restrict__ lnw,
                       unsigned long long* __restrict__ diff_acc,
                       const int* __restrict__ conv) {
    __shared__ float qs[64][68];    // qp transposed: qs[d][m]
    __shared__ float kps[64][68];   // phase A: lqw^T; loop: k^T then P^T
    __shared__ float vs[64][68];    // phase A: q tile^T; loop: v chunk
    __shared__ float dred[4];
    int blk = blockIdx.x;
    int t = blk & 7;
    int u = blk >> 3;
    int h = u & 15;
    int w = (u >> 4) & 7;
    int b = u >> 7;
    if (USE_CONV && conv[w]) return;
    int rowbase = b * CTX + w * WIN;
    int col0 = h * HD;
    int tid = threadIdx.x;
    int tm = tid >> 4, tn = tid & 15;

    // ---- phase A: compute qp tile in-block ----
    for (int e = tid; e < 4096; e += 256) kps[e & 63][e >> 6] = lqw[e];  // kps[i][n]=lqw[n][i]
    for (int e = tid; e < 1024; e += 256) {
        int row = e >> 4;
        int col = (e & 15) << 2;
        float4 v = ld4(qacc + (size_t)(rowbase + t * 64 + row) * DIMS + col0 + col);
        vs[col + 0][row] = v.x; vs[col + 1][row] = v.y;
        vs[col + 2][row] = v.z; vs[col + 3][row] = v.w;   // vs[i][m] = q[m][i]
    }
    __syncthreads();
    {
        float acc[4][4] = {};
#pragma unroll
        for (int k = 0; k < 64; ++k) {
            float4 av = ld4(&vs[k][tm << 2]);
            float4 bv = ld4(&kps[k][tn << 2]);
            float aa[4] = {av.x, av.y, av.z, av.w};
            float bb[4] = {bv.x, bv.y, bv.z, bv.w};
#pragma unroll
            for (int mm = 0; mm < 4; ++mm)
#pragma unroll
                for (int nn = 0; nn < 4; ++nn)
                    acc[mm][nn] = fmaf(aa[mm], bb[nn], acc[mm][nn]);
        }
        float bb4[4] = {lqb[(tn << 2) + 0], lqb[(tn << 2) + 1],
                        lqb[(tn << 2) + 2], lqb[(tn << 2) + 3]};
        float lw4[4] = {lnw[(tn << 2) + 0], lnw[(tn << 2) + 1],
                        lnw[(tn << 2) + 2], lnw[(tn << 2) + 3]};
#pragma unroll
        for (int mm = 0; mm < 4; ++mm) {
            float o0 = acc[mm][0] + bb4[0], o1 = acc[mm][1] + bb4[1];
            float o2 = acc[mm][2] + bb4[2], o3 = acc[mm][3] + bb4[3];
            float mean = grp16_sum(o0 + o1 + o2 + o3) * (1.0f / 64.0f);
            float d0 = o0 - mean, d1 = o1 - mean, d2 = o2 - mean, d3 = o3 - mean;
            float var = grp16_sum(d0*d0 + d1*d1 + d2*d2 + d3*d3) * (1.0f / 64.0f);
            float inv = rsqrtf(var + LNEPS);
            int m = (tm << 2) + mm;
            qs[(tn << 2) + 0][m] = d0 * inv * lw4[0];
            qs[(tn << 2) + 1][m] = d1 * inv * lw4[1];
            qs[(tn << 2) + 2][m] = d2 * inv * lw4[2];
            qs[(tn << 2) + 3][m] = d3 * inv * lw4[3];
        }
    }

    // ---- flash loop over causal chunks ----
    float m_r[4], l_r[4], o_acc[4][4];
#pragma unroll
    for (int i = 0; i < 4; ++i) {
        m_r[i] = -INFINITY; l_r[i] = 0.0f;
#pragma unroll
        for (int j = 0; j < 4; ++j) o_acc[i][j] = 0.0f;
    }

    for (int c = 0; c <= t; ++c) {
        __syncthreads();   // phase-A/prev-PV reads of kps/vs done; qs visible
        for (int e = tid; e < 1024; e += 256) {
            int row = e >> 4;
            int col = (e & 15) << 2;
            float4 kv = ld4(kp + (size_t)(rowbase + c * 64 + row) * DIMS + col0 + col);
            kps[col + 0][row] = kv.x; kps[col + 1][row] = kv.y;
            kps[col + 2][row] = kv.z; kps[col + 3][row] = kv.w;
            float4 vv = ld4(vp + (size_t)(rowbase + c * 64 + row) * DIMS + col0 + col);
            st4(&vs[row][col], vv);
        }
        __syncthreads();

        float s_acc[4][4] = {};
#pragma unroll
        for (int k = 0; k < 64; ++k) {
            float4 av = ld4(&qs[k][tm << 2]);
            float4 bv = ld4(&kps[k][tn << 2]);
            float aa[4] = {av.x, av.y, av.z, av.w};
            float bb[4] = {bv.x, bv.y, bv.z, bv.w};
#pragma unroll
            for (int mm = 0; mm < 4; ++mm)
#pragma unroll
                for (int nn = 0; nn < 4; ++nn)
                    s_acc[mm][nn] = fmaf(aa[mm], bb[nn], s_acc[mm][nn]);
        }
        __syncthreads();   // all QK reads of kps done; safe to overwrite with ps

        float pvv[4][4];
#pragma unroll
        for (int mm = 0; mm < 4; ++mm) {
            int srow = t * 64 + (tm << 2) + mm;
            float sv[4];
            float mx = -INFINITY;
#pragma unroll
            for (int nn = 0; nn < 4; ++nn) {
                int key = c * 64 + (tn << 2) + nn;
                float scv = (key <= srow) ? s_acc[mm][nn] * 0.125f : -INFINITY;
                sv[nn] = scv;
                mx = fmaxf(mx, scv);
            }
            mx = grp16_max(mx);
            float mnew = fmaxf(m_r[mm], mx);
            float psum = 0.0f;
#pragma unroll
            for (int nn = 0; nn < 4; ++nn) {
                float p = expf(sv[nn] - mnew);
                pvv[mm][nn] = p;
                psum += p;
            }
            psum = grp16_sum(psum);
            float ef = expf(m_r[mm] - mnew);
            l_r[mm] = l_r[mm] * ef + psum;
            m_r[mm] = mnew;
#pragma unroll
            for (int dd = 0; dd < 4; ++dd) o_acc[mm][dd] *= ef;
        }
#pragma unroll
        for (int mm = 0; mm < 4; ++mm)
#pragma unroll
            for (int nn = 0; nn < 4; ++nn)
                kps[(tn << 2) + nn][(tm << 2) + mm] = pvv[mm][nn];
        __syncthreads();

#pragma unroll
        for (int j = 0; j < 64; ++j) {
            float4 av = ld4(&kps[j][tm << 2]);
            float4 bv = ld4(&vs[j][tn << 2]);
            float aa[4] = {av.x, av.y, av.z, av.w};
            float bb[4] = {bv.x, bv.y, bv.z, bv.w};
#pragma unroll
            for (int mm = 0; mm < 4; ++mm)
#pragma unroll
                for (int dd = 0; dd < 4; ++dd)
                    o_acc[mm][dd] = fmaf(aa[mm], bb[dd], o_acc[mm][dd]);
        }
    }

    // ---- epilogue: finalize, optional diff vs previous contents, store ----
    float dsum = 0.0f;
#pragma unroll
    for (int mm = 0; mm < 4; ++mm) {
        int srow = t * 64 + (tm << 2) + mm;
        float invl = 1.0f / l_r[mm];
        float4 ov = make_float4(o_acc[mm][0] * invl, o_acc[mm][1] * invl,
                                o_acc[mm][2] * invl, o_acc[mm][3] * invl);
        float* addr = o_io + (size_t)(rowbase + srow) * DIMS + col0 + (tn << 2);
        if (DIFF) {
            float4 pv = ld4(addr);
            dsum += fabsf(ov.x - pv.x) + fabsf(ov.y - pv.y)
                  + fabsf(ov.z - pv.z) + fabsf(ov.w - pv.w);
        }
        st4(addr, ov);
    }
    if (DIFF) {
        float s = wave_sum64(dsum);
        int wv = tid >> 6, lane = tid & 63;
        if (lane == 0) dred[wv] = s;
        __syncthreads();
        if (tid == 0) {
            double tot = (double)(dred[0] + dred[1] + dred[2] + dred[3]);
            unsigned long long q = (unsigned long long)(tot * FIXSCALE + 0.5);
            atomicAdd(&diff_acc[w], q);
        }
    }
}

// -------- qacc[u,:] += scramble(o)[u,:]  (torch q_cur += iter_out) -----------
__global__ __launch_bounds__(256)
void scatter_add_kernel(float* __restrict__ qacc, const float* __restrict__ o) {
    size_t gid = (size_t)blockIdx.x * 256 + threadIdx.x;
    size_t flat = gid << 2;              // element index (r*1024 + h*64 + d)
    int u = (int)(flat >> 6);
    int col = (int)(flat & 63);
    int r = u >> 4, h = u & 15;
    int s = r & 511;
    int rb = r - s;                      // b*4096 + w*512
    size_t src = ((size_t)(rb + h * 32 + (s >> 4)) << 10)
               + (size_t)((s & 15) << 6) + col;
    float4 a = ld4(qacc + flat);
    float4 bv = ld4(o + src);
    st4(qacc + flat, make_float4(a.x + bv.x, a.y + bv.y, a.z + bv.z, a.w + bv.w));
}

// -------- control init: zero diff accumulators + conv flags ------------------
__global__ void init_ctrl_kernel(unsigned long long* __restrict__ dacc,
                                 int* __restrict__ conv) {
    int i = threadIdx.x;
    if (i < 8) { dacc[i] = 0ULL; conv[i] = 0; }
}

// -------- conv flags from fixed-point accumulators ---------------------------
__global__ void conv_from_acc_kernel(const unsigned long long* __restrict__ dacc,
                                     int* __restrict__ conv) {
    int w = threadIdx.x;
    if (w < 8) {
        float mean = (float)((double)dacc[w] * (1.0 / (FIXSCALE * 2097152.0)));
        conv[w] = (mean < 0.01f + 0.1f * mean) ? 1 : 0;
    }
}

// -------- unscramble src into preout [B,S,DIMS] ------------------------------
// out[r, h2*64+d2] = src[(rb + h2*32 + s2/16)*1024 + (s2%16)*64 + d2]
__global__ __launch_bounds__(256)
void unscramble_kernel(const float* __restrict__ src, float* __restrict__ outp) {
    size_t gid = (size_t)blockIdx.x * 256 + threadIdx.x;
    size_t flat = gid << 2;
    int r = (int)(flat >> 10);
    int e = (int)(flat & 1023);
    int h2 = e >> 6, d2 = e & 63;
    int s2 = r & 511;
    int rb = r - s2;
    size_t sidx = ((size_t)(rb + h2 * 32 + (s2 >> 4)) << 10) + (size_t)((s2 & 15) << 6) + d2;
    st4(outp + flat, ld4(src + sidx));
}

extern "C" void kernel_launch(void* const* d_in, const int* in_sizes, int n_in,
                              void* d_out, int out_size, void* d_ws, size_t ws_size,
                              hipStream_t stream) {
    (void)in_sizes; (void)n_in; (void)out_size; (void)ws_size;
    const float* x   = (const float*)d_in[0];
    const float* Wq  = (const float*)d_in[1];
    const float* bq  = (const float*)d_in[2];
    const float* Wk  = (const float*)d_in[3];
    const float* Wv  = (const float*)d_in[4];
    const float* bv  = (const float*)d_in[5];
    const float* Wo  = (const float*)d_in[6];
    const float* bo  = (const float*)d_in[7];
    const float* lna = (const float*)d_in[8];
    const float* lnb = (const float*)d_in[9];
    const float* lqw = (const float*)d_in[10];
    const float* lqb = (const float*)d_in[11];
    const float* lkw = (const float*)d_in[12];
    const float* lkb = (const float*)d_in[13];
    const float* lvw = (const float*)d_in[14];
    const float* lvb = (const float*)d_in[15];

    // ws layout: [4 KiB control][W1 qacc][W2 k/kp/preout][W3 v/vp] = 192 MiB + 4 KiB
    const size_t BUF = (size_t)NROWS * DIMS;      // 16M floats
    unsigned long long* dacc = (unsigned long long*)d_ws;   // 8 x u64
    int* conv = (int*)(dacc + 8);                            // 8 x int
    float* W1 = (float*)((char*)d_ws + 4096);
    float* W2 = W1 + BUF;
    float* W3 = W2 + BUF;
    float* E  = (float*)d_out;     // xn -> o0 -> o1 -> o1/o2 selected -> final out

    const float scale = 0.35355339059327373f;     // 64^-0.25

    // 1. xn = LN(x) into d_out
    ln1024_kernel<<<NROWS, 256, 0, stream>>>(x, lna, E);

    // 2. q,k,v GEMMs (xn dead after these)
    dim3 gg(NROWS / 128, DIMS / 128);
    gemm_nt_kernel<<<gg, 256, 0, stream>>>(E, Wq, bq,      W1, NROWS, DIMS, DIMS, scale, 1);
    gemm_nt_kernel<<<gg, 256, 0, stream>>>(E, Wk, nullptr, W2, NROWS, DIMS, DIMS, scale, 0);
    gemm_nt_kernel<<<gg, 256, 0, stream>>>(E, Wv, bv,      W3, NROWS, DIMS, DIMS, 1.0f, 1);

    // 3. per-head LN on q,k
    headln_kernel<<<NUNITS / 4, 256, 0, stream>>>(W1, W2, lnb);

    // 4. iteration-invariant kp, vp (in place)
    proj64_kernel<1><<<NUNITS / 64, 256, 0, stream>>>(W2, lkw, lkb, lnb, W2);
    proj64_kernel<0><<<NUNITS / 64, 256, 0, stream>>>(W3, lvw, lvb, lnb, W3);

    // 5. zero diff accumulators + conv flags (must happen every call)
    init_ctrl_kernel<<<1, 64, 0, stream>>>(dacc, conv);

    // 6. it 0: o0 -> E (qp fused from qacc=W1)
    attn_fused_kernel<0, 0><<<512 * 8, 256, 0, stream>>>(W1, W2, W3, E, lqw, lqb, lnb, dacc, conv);
    // 7. qacc += scr(o0)
    scatter_add_kernel<<<NROWS * DIMS / 4 / 256, 256, 0, stream>>>(W1, E);
    // 8. it 1: o1 -> E in place, fused per-window diff vs o0
    attn_fused_kernel<1, 0><<<512 * 8, 256, 0, stream>>>(W1, W2, W3, E, lqw, lqb, lnb, dacc, conv);
    // 9. conv flags
    conv_from_acc_kernel<<<1, 64, 0, stream>>>(dacc, conv);
    // 10. qacc += scr(o1)  (harmless for converged windows; unused there)
    scatter_add_kernel<<<NROWS * DIMS / 4 / 256, 256, 0, stream>>>(W1, E);
    // 11. it 2: o2 -> E in place, skipped for converged windows (E keeps o1)
    attn_fused_kernel<0, 1><<<512 * 8, 256, 0, stream>>>(W1, W2, W3, E, lqw, lqb, lnb, dacc, conv);

    // 12. preout = unscramble(E) -> W2 (kp dead)
    unscramble_kernel<<<NROWS * DIMS / 4 / 256, 256, 0, stream>>>(E, W2);
    // 13. out = preout @ Wo^T + bo
    gemm_nt_kernel<<<gg, 256, 0, stream>>>(W2, Wo, bo, (float*)d_out, NROWS, DIMS, DIMS, 1.0f, 1);
}

// Round 4
// 3159.423 us; speedup vs baseline: 1.7078x; 1.7078x over previous
//
#include <hip/hip_runtime.h>
#include <math.h>

// Problem constants (from reference)
#define DIMS   1024
#define NHEAD  16
#define HD     64
#define WIN    512
#define CTX    4096
#define NBATCH 4
#define NROWS  (NBATCH*CTX)        // 16384 total sequence rows
#define NUNITS (NROWS*NHEAD)       // 262144 (row,head) units
#define LNEPS  1e-5f
#define FIXSCALE 16777216.0        // 2^24 fixed-point for deterministic diff

typedef __attribute__((ext_vector_type(8))) short bf16x8;   // 8 bf16 (4 VGPR)
typedef __attribute__((ext_vector_type(4))) float f32x4;    // MFMA C/D

__device__ __forceinline__ float4 ld4(const float* p) { return *reinterpret_cast<const float4*>(p); }
__device__ __forceinline__ void st4(float* p, float4 v) { *reinterpret_cast<float4*>(p) = v; }

__device__ __forceinline__ float wave_sum64(float v) {
#pragma unroll
    for (int off = 32; off; off >>= 1) v += __shfl_xor(v, off, 64);
    return v;
}
__device__ __forceinline__ float grp16_sum(float v) {
    v += __shfl_xor(v, 1, 64);
    v += __shfl_xor(v, 2, 64);
    v += __shfl_xor(v, 4, 64);
    v += __shfl_xor(v, 8, 64);
    return v;
}

// round-to-nearest-even bf16 of x, packed split: (hi<<16)|lo with hi+lo ~= x (err ~2^-17)
__device__ __forceinline__ unsigned bf16_rn_bits(float x) {
    unsigned u = __float_as_uint(x);
    return (u + 0x7fffu + ((u >> 16) & 1u)) >> 16;
}
__device__ __forceinline__ unsigned pack_hl(float x) {
    unsigned h = bf16_rn_bits(x);
    float hf = __uint_as_float(h << 16);
    unsigned l = bf16_rn_bits(x - hf);
    return (h << 16) | (l & 0xffffu);
}

// -------- LayerNorm over D=1024 (row-wise) -----------------------------------
__global__ __launch_bounds__(256)
void ln1024_kernel(const float* __restrict__ x, const float* __restrict__ w,
                   float* __restrict__ outp) {
    int r = blockIdx.x;
    int tid = threadIdx.x;
    const float* xr = x + (size_t)r * DIMS;
    float4 v = ld4(xr + (tid << 2));
    __shared__ float red[8];
    float s = wave_sum64(v.x + v.y + v.z + v.w);
    int wv = tid >> 6, lane = tid & 63;
    if (lane == 0) red[wv] = s;
    __syncthreads();
    float mean = (red[0] + red[1] + red[2] + red[3]) * (1.0f / DIMS);
    float dx = v.x - mean, dy = v.y - mean, dz = v.z - mean, dw = v.w - mean;
    float ss = wave_sum64(dx*dx + dy*dy + dz*dz + dw*dw);
    if (lane == 0) red[4 + wv] = ss;
    __syncthreads();
    float inv = rsqrtf((red[4] + red[5] + red[6] + red[7]) * (1.0f / DIMS) + LNEPS);
    float4 wv4 = ld4(w + (tid << 2));
    st4(outp + (size_t)r * DIMS + (tid << 2),
        make_float4(dx * inv * wv4.x, dy * inv * wv4.y, dz * inv * wv4.z, dw * inv * wv4.w));
}

// -------- fp32 GEMM  C[m,n] = alpha*(sum_k A[m,k]*W[n,k] + bias[n]) ----------
__global__ __launch_bounds__(256)
void gemm_nt_kernel(const float* __restrict__ A, const float* __restrict__ W,
                    const float* __restrict__ bias, float* __restrict__ Cm,
                    int M, int N, int K, float alpha, int has_bias) {
    __shared__ float As[16][132];
    __shared__ float Bs[16][132];
    int bm = blockIdx.x, bn = blockIdx.y;
    int tid = threadIdx.x;
    int tm = tid >> 4, tn = tid & 15;
    int lr = tid >> 2;
    int lc = (tid & 3) << 2;
    const float* Ag = A + (size_t)bm * 128 * K;
    const float* Wg = W + (size_t)bn * 128 * K;
    float acc[8][8] = {};
    for (int k0 = 0; k0 < K; k0 += 16) {
        float4 a0 = ld4(Ag + (size_t)lr * K + k0 + lc);
        float4 a1 = ld4(Ag + (size_t)(lr + 64) * K + k0 + lc);
        float4 b0 = ld4(Wg + (size_t)lr * K + k0 + lc);
        float4 b1 = ld4(Wg + (size_t)(lr + 64) * K + k0 + lc);
        __syncthreads();
        As[lc+0][lr] = a0.x; As[lc+1][lr] = a0.y; As[lc+2][lr] = a0.z; As[lc+3][lr] = a0.w;
        As[lc+0][lr+64] = a1.x; As[lc+1][lr+64] = a1.y; As[lc+2][lr+64] = a1.z; As[lc+3][lr+64] = a1.w;
        Bs[lc+0][lr] = b0.x; Bs[lc+1][lr] = b0.y; Bs[lc+2][lr] = b0.z; Bs[lc+3][lr] = b0.w;
        Bs[lc+0][lr+64] = b1.x; Bs[lc+1][lr+64] = b1.y; Bs[lc+2][lr+64] = b1.z; Bs[lc+3][lr+64] = b1.w;
        __syncthreads();
#pragma unroll
        for (int kk = 0; kk < 16; ++kk) {
            float a[8], bv[8];
            *reinterpret_cast<float4*>(&a[0])  = ld4(&As[kk][tm << 3]);
            *reinterpret_cast<float4*>(&a[4])  = ld4(&As[kk][(tm << 3) + 4]);
            *reinterpret_cast<float4*>(&bv[0]) = ld4(&Bs[kk][tn << 3]);
            *reinterpret_cast<float4*>(&bv[4]) = ld4(&Bs[kk][(tn << 3) + 4]);
#pragma unroll
            for (int i = 0; i < 8; ++i)
#pragma unroll
                for (int j = 0; j < 8; ++j)
                    acc[i][j] = fmaf(a[i], bv[j], acc[i][j]);
        }
    }
    int m0 = bm * 128 + (tm << 3);
    int n0 = bn * 128 + (tn << 3);
    float bb[8];
#pragma unroll
    for (int j = 0; j < 8; ++j) bb[j] = has_bias ? bias[n0 + j] : 0.0f;
#pragma unroll
    for (int i = 0; i < 8; ++i) {
        float o[8];
#pragma unroll
        for (int j = 0; j < 8; ++j) o[j] = alpha * (acc[i][j] + bb[j]);
        st4(Cm + (size_t)(m0 + i) * N + n0,     make_float4(o[0], o[1], o[2], o[3]));
        st4(Cm + (size_t)(m0 + i) * N + n0 + 4, make_float4(o[4], o[5], o[6], o[7]));
    }
}

// -------- per-(row,head) LayerNorm over d=64, in place on q and k ------------
__global__ __launch_bounds__(256)
void headln_kernel(float* __restrict__ q, float* __restrict__ k,
                   const float* __restrict__ lnw) {
    int gw = (blockIdx.x << 2) + (threadIdx.x >> 6);
    int lane = threadIdx.x & 63;
    size_t idx = ((size_t)gw << 6) + lane;
    float wgt = lnw[lane];
    {
        float v = q[idx];
        float mean = wave_sum64(v) * (1.0f / 64.0f);
        float d = v - mean;
        float var = wave_sum64(d * d) * (1.0f / 64.0f);
        q[idx] = d * rsqrtf(var + LNEPS) * wgt;
    }
    {
        float v = k[idx];
        float mean = wave_sum64(v) * (1.0f / 64.0f);
        float d = v - mean;
        float var = wave_sum64(d * d) * (1.0f / 64.0f);
        k[idx] = d * rsqrtf(var + LNEPS) * wgt;
    }
}

// -------- kp projection + LN + hi/lo split -> packed K plane -----------------
// K plane layout: u32 khl[unit*512 + s][64] where unit = (b*8+w)*16+h
__global__ __launch_bounds__(256)
void proj64_khl_kernel(const float* __restrict__ inp, const float* __restrict__ W,
                       const float* __restrict__ Wb, const float* __restrict__ lnw,
                       unsigned* __restrict__ plane) {
    int u0 = blockIdx.x << 6;
    __shared__ float As[64][68];
    __shared__ float Bs[64][68];
    int tid = threadIdx.x;
    for (int e = tid; e < 4096; e += 256) Bs[e & 63][e >> 6] = W[e];
    for (int e = tid; e < 1024; e += 256) {
        int row = e >> 4;
        int col = (e & 15) << 2;
        float4 v = ld4(inp + ((size_t)(u0 + row) << 6) + col);
        As[col + 0][row] = v.x; As[col + 1][row] = v.y;
        As[col + 2][row] = v.z; As[col + 3][row] = v.w;
    }
    __syncthreads();
    int tm = tid >> 4, tn = tid & 15;
    float acc[4][4] = {};
#pragma unroll
    for (int k = 0; k < 64; ++k) {
        float4 av = ld4(&As[k][tm << 2]);
        float4 bv = ld4(&Bs[k][tn << 2]);
        float aa[4] = {av.x, av.y, av.z, av.w};
        float bb[4] = {bv.x, bv.y, bv.z, bv.w};
#pragma unroll
        for (int mm = 0; mm < 4; ++mm)
#pragma unroll
            for (int nn = 0; nn < 4; ++nn)
                acc[mm][nn] = fmaf(aa[mm], bb[nn], acc[mm][nn]);
    }
    float bb4[4] = {Wb[(tn << 2) + 0], Wb[(tn << 2) + 1], Wb[(tn << 2) + 2], Wb[(tn << 2) + 3]};
    float lw4[4] = {lnw[(tn << 2) + 0], lnw[(tn << 2) + 1], lnw[(tn << 2) + 2], lnw[(tn << 2) + 3]};
#pragma unroll
    for (int mm = 0; mm < 4; ++mm) {
        float o0 = acc[mm][0] + bb4[0], o1 = acc[mm][1] + bb4[1];
        float o2 = acc[mm][2] + bb4[2], o3 = acc[mm][3] + bb4[3];
        float mean = grp16_sum(o0 + o1 + o2 + o3) * (1.0f / 64.0f);
        float d0 = o0 - mean, d1 = o1 - mean, d2 = o2 - mean, d3 = o3 - mean;
        float var = grp16_sum(d0*d0 + d1*d1 + d2*d2 + d3*d3) * (1.0f / 64.0f);
        float inv = rsqrtf(var + LNEPS);
        o0 = d0 * inv * lw4[0]; o1 = d1 * inv * lw4[1];
        o2 = d2 * inv * lw4[2]; o3 = d3 * inv * lw4[3];
        int u_p = u0 + (tm << 2) + mm;
        int r = u_p >> 4, h = u_p & 15;
        int s = r & 511;
        int ua = ((r >> 9) << 4) + h;
        size_t punit = (size_t)ua * 512 + s;
        uint4 pk;
        pk.x = pack_hl(o0); pk.y = pack_hl(o1); pk.z = pack_hl(o2); pk.w = pack_hl(o3);
        *reinterpret_cast<uint4*>(plane + (punit << 6) + (tn << 2)) = pk;
    }
}

// -------- vp projection + hi/lo split -> packed transposed V plane -----------
// VT plane layout: u32 vthl[(unit*8 + chunk)*64 + d][64 j]
__global__ __launch_bounds__(256)
void proj64_vthl_kernel(const float* __restrict__ inp, const float* __restrict__ W,
                        const float* __restrict__ Wb, unsigned* __restrict__ plane) {
    int u0 = blockIdx.x << 6;
    __shared__ float As[64][68];
    __shared__ float Bs[64][68];
    int tid = threadIdx.x;
    for (int e = tid; e < 4096; e += 256) Bs[e & 63][e >> 6] = W[e];
    for (int e = tid; e < 1024; e += 256) {
        int row = e >> 4;
        int col = (e & 15) << 2;
        float4 v = ld4(inp + ((size_t)(u0 + row) << 6) + col);
        As[col + 0][row] = v.x; As[col + 1][row] = v.y;
        As[col + 2][row] = v.z; As[col + 3][row] = v.w;
    }
    __syncthreads();
    int tm = tid >> 4, tn = tid & 15;
    float acc[4][4] = {};
#pragma unroll
    for (int k = 0; k < 64; ++k) {
        float4 av = ld4(&As[k][tm << 2]);
        float4 bv = ld4(&Bs[k][tn << 2]);
        float aa[4] = {av.x, av.y, av.z, av.w};
        float bb[4] = {bv.x, bv.y, bv.z, bv.w};
#pragma unroll
        for (int mm = 0; mm < 4; ++mm)
#pragma unroll
            for (int nn = 0; nn < 4; ++nn)
                acc[mm][nn] = fmaf(aa[mm], bb[nn], acc[mm][nn]);
    }
    float bb4[4] = {Wb[(tn << 2) + 0], Wb[(tn << 2) + 1], Wb[(tn << 2) + 2], Wb[(tn << 2) + 3]};
#pragma unroll
    for (int mm = 0; mm < 4; ++mm) {
        int u_p = u0 + (tm << 2) + mm;
        int r = u_p >> 4, h = u_p & 15;
        int s = r & 511;
        int ua = ((r >> 9) << 4) + h;
        size_t base = ((size_t)(ua * 8 + (s >> 6)) << 12) + (s & 63);
#pragma unroll
        for (int nn = 0; nn < 4; ++nn) {
            int d = (tn << 2) + nn;
            plane[base + ((size_t)d << 6)] = pack_hl(acc[mm][nn] + bb4[nn]);
        }
    }
}

// -------- fused MFMA attention ----------------------------------------------
// blockIdx.x = unit*8 + qtile.  qp = LN(qacc@lqw^T+lqb) computed in-block (fp32),
// S^T = mfma(K,Q) and O^T = mfma(V^T,P^T) with bf16 hi/lo 3-term products.
template<int DIFF, int USE_CONV>
__global__ __launch_bounds__(256)
void attn_mfma_kernel(const float* __restrict__ qacc, const unsigned* __restrict__ khl,
                      const unsigned* __restrict__ vthl, float* __restrict__ o_io,
                      const float* __restrict__ lqw, const float* __restrict__ lqb,
                      const float* __restrict__ lnw,
                      unsigned long long* __restrict__ diff_acc,
                      const int* __restrict__ conv) {
    __shared__ union {
        struct { float lq[64][68]; float qt[64][68]; float qs[64][68]; } a;  // phase A
        struct { short kh[64][72], kl[64][72], vh[64][72], vl[64][72]; } b;  // chunk loop
    } sm;
    __shared__ float dred[4];

    int blk = blockIdx.x;
    int t = blk & 7;
    int u = blk >> 3;
    int h = u & 15;
    int w = (u >> 4) & 7;
    int b = u >> 7;
    if (USE_CONV && conv[w]) return;
    int rowbase = b * CTX + w * WIN;
    int col0 = h * HD;
    int tid = threadIdx.x;
    int tm = tid >> 4, tn = tid & 15;
    int wv = tid >> 6;
    int lane = tid & 63;
    int g4 = lane >> 4;
    int qcol = lane & 15;
    int q_loc = (wv << 4) + qcol;   // this lane's query row within the 64-row tile

    // ---- phase A: qp = LN(qacc @ lqw^T + lqb), fp32, -> sm.a.qs[d][m] ----
    for (int e = tid; e < 4096; e += 256) sm.a.lq[e & 63][e >> 6] = lqw[e];
    for (int e = tid; e < 1024; e += 256) {
        int row = e >> 4;
        int col = (e & 15) << 2;
        float4 v = ld4(qacc + (size_t)(rowbase + (t << 6) + row) * DIMS + col0 + col);
        sm.a.qt[col + 0][row] = v.x; sm.a.qt[col + 1][row] = v.y;
        sm.a.qt[col + 2][row] = v.z; sm.a.qt[col + 3][row] = v.w;
    }
    __syncthreads();
    {
        float acc[4][4] = {};
#pragma unroll
        for (int k = 0; k < 64; ++k) {
            float4 av = ld4(&sm.a.qt[k][tm << 2]);
            float4 bv = ld4(&sm.a.lq[k][tn << 2]);
            float aa[4] = {av.x, av.y, av.z, av.w};
            float bb[4] = {bv.x, bv.y, bv.z, bv.w};
#pragma unroll
            for (int mm = 0; mm < 4; ++mm)
#pragma unroll
                for (int nn = 0; nn < 4; ++nn)
                    acc[mm][nn] = fmaf(aa[mm], bb[nn], acc[mm][nn]);
        }
        float bb4[4] = {lqb[(tn << 2) + 0], lqb[(tn << 2) + 1],
                        lqb[(tn << 2) + 2], lqb[(tn << 2) + 3]};
        float lw4[4] = {lnw[(tn << 2) + 0], lnw[(tn << 2) + 1],
                        lnw[(tn << 2) + 2], lnw[(tn << 2) + 3]};
#pragma unroll
        for (int mm = 0; mm < 4; ++mm) {
            float o0 = acc[mm][0] + bb4[0], o1 = acc[mm][1] + bb4[1];
            float o2 = acc[mm][2] + bb4[2], o3 = acc[mm][3] + bb4[3];
            float mean = grp16_sum(o0 + o1 + o2 + o3) * (1.0f / 64.0f);
            float d0 = o0 - mean, d1 = o1 - mean, d2 = o2 - mean, d3 = o3 - mean;
            float var = grp16_sum(d0*d0 + d1*d1 + d2*d2 + d3*d3) * (1.0f / 64.0f);
            float inv = rsqrtf(var + LNEPS);
            int m = (tm << 2) + mm;
            sm.a.qs[(tn << 2) + 0][m] = d0 * inv * lw4[0];
            sm.a.qs[(tn << 2) + 1][m] = d1 * inv * lw4[1];
            sm.a.qs[(tn << 2) + 2][m] = d2 * inv * lw4[2];
            sm.a.qs[(tn << 2) + 3][m] = d3 * inv * lw4[3];
        }
    }
    __syncthreads();

    // ---- build Q B-fragments (hi/lo) in registers: qp[q_loc][d], d=kb*32+g4*8+i
    bf16x8 qfh[2], qfl[2];
#pragma unroll
    for (int kb = 0; kb < 2; ++kb)
#pragma unroll
        for (int i = 0; i < 8; ++i) {
            float v = sm.a.qs[(kb << 5) + (g4 << 3) + i][q_loc];
            unsigned hb = bf16_rn_bits(v);
            float hf = __uint_as_float(hb << 16);
            unsigned lb = bf16_rn_bits(v - hf);
            qfh[kb][i] = (short)hb;
            qfl[kb][i] = (short)lb;
        }
    __syncthreads();   // qs reads done; LDS reused for K/V staging

    // ---- flash loop ----
    float m_r = -INFINITY, l_r = 0.0f;
    f32x4 oacc[4] = {{0,0,0,0},{0,0,0,0},{0,0,0,0},{0,0,0,0}};
    const unsigned* kbase = khl + (((size_t)u * 512) << 6);
    const unsigned* vbase = vthl + (((size_t)u * 8) << 12);

    for (int c = 0; c <= t; ++c) {
        // stage chunk: K rows (j) and VT rows (d), packed u32 -> unpack hi/lo bf16
        const unsigned* ksrc = kbase + (((size_t)c * 64) << 6);
        const unsigned* vsrc = vbase + (((size_t)c) << 12);
#pragma unroll
        for (int rr = 0; rr < 4; ++rr) {
            int row = (wv << 4) + (rr << 2) + g4;
            uint4 pk = *reinterpret_cast<const uint4*>(ksrc + ((size_t)row << 6) + (qcol << 2));
            unsigned* khp = reinterpret_cast<unsigned*>(&sm.b.kh[row][qcol << 2]);
            khp[0] = __byte_perm(pk.x, pk.y, 0x7632);
            khp[1] = __byte_perm(pk.z, pk.w, 0x7632);
            unsigned* klp = reinterpret_cast<unsigned*>(&sm.b.kl[row][qcol << 2]);
            klp[0] = __byte_perm(pk.x, pk.y, 0x5410);
            klp[1] = __byte_perm(pk.z, pk.w, 0x5410);
            uint4 pv = *reinterpret_cast<const uint4*>(vsrc + ((size_t)row << 6) + (qcol << 2));
            unsigned* vhp = reinterpret_cast<unsigned*>(&sm.b.vh[row][qcol << 2]);
            vhp[0] = __byte_perm(pv.x, pv.y, 0x7632);
            vhp[1] = __byte_perm(pv.z, pv.w, 0x7632);
            unsigned* vlp = reinterpret_cast<unsigned*>(&sm.b.vl[row][qcol << 2]);
            vlp[0] = __byte_perm(pv.x, pv.y, 0x5410);
            vlp[1] = __byte_perm(pv.z, pv.w, 0x5410);
        }
        __syncthreads();

        // S^T = K * Q^T  (A = K rows j, B = Q cols q) with 3-term hi/lo
        f32x4 sacc[4] = {{0,0,0,0},{0,0,0,0},{0,0,0,0},{0,0,0,0}};
#pragma unroll
        for (int jt = 0; jt < 4; ++jt) {
            int jrow = (jt << 4) + qcol;
#pragma unroll
            for (int kb = 0; kb < 2; ++kb) {
                bf16x8 ah = *reinterpret_cast<const bf16x8*>(&sm.b.kh[jrow][(kb << 5) + (g4 << 3)]);
                bf16x8 al = *reinterpret_cast<const bf16x8*>(&sm.b.kl[jrow][(kb << 5) + (g4 << 3)]);
                sacc[jt] = __builtin_amdgcn_mfma_f32_16x16x32_bf16(ah, qfh[kb], sacc[jt], 0, 0, 0);
                sacc[jt] = __builtin_amdgcn_mfma_f32_16x16x32_bf16(al, qfh[kb], sacc[jt], 0, 0, 0);
                sacc[jt] = __builtin_amdgcn_mfma_f32_16x16x32_bf16(ah, qfl[kb], sacc[jt], 0, 0, 0);
            }
        }

        // online softmax: lane owns query q_loc; its 16 S^T values at
        // j_loc = jt*16 + g4*4 + r, replicated state across 4 lane-groups.
        float sv[16];
        float mx = -3.0e38f;
#pragma unroll
        for (int jt = 0; jt < 4; ++jt)
#pragma unroll
            for (int r = 0; r < 4; ++r) {
                float s = sacc[jt][r] * 0.125f;
                if (c == t) {
                    int j_loc = (jt << 4) + (g4 << 2) + r;
                    if (j_loc > q_loc) s = -3.0e38f;
                }
                sv[(jt << 2) + r] = s;
                mx = fmaxf(mx, s);
            }
        mx = fmaxf(mx, __shfl_xor(mx, 16, 64));
        mx = fmaxf(mx, __shfl_xor(mx, 32, 64));
        float mnew = fmaxf(m_r, mx);
        float ps = 0.0f;
        unsigned pu[16];
#pragma unroll
        for (int e = 0; e < 16; ++e) {
            float p = __expf(sv[e] - mnew);
            ps += p;
            pu[e] = pack_hl(p);
        }
        ps += __shfl_xor(ps, 16, 64);
        ps += __shfl_xor(ps, 32, 64);
        float ef = __expf(m_r - mnew);
        l_r = l_r * ef + ps;
        m_r = mnew;
#pragma unroll
        for (int dt = 0; dt < 4; ++dt) oacc[dt] *= ef;

        // O^T += V^T * P^T.  P^T B-frags assembled in-register via shfl.
#pragma unroll
        for (int kb2 = 0; kb2 < 2; ++kb2) {
            unsigned w0[8];
#pragma unroll
            for (int i = 0; i < 8; ++i) {
                int src = ((((g4 & 1) << 1) + (i >> 2)) << 4) | qcol;
                unsigned vA = __shfl(pu[((kb2 << 1) + 0) * 4 + (i & 3)], src, 64);
                unsigned vB = __shfl(pu[((kb2 << 1) + 1) * 4 + (i & 3)], src, 64);
                w0[i] = (g4 >> 1) ? vB : vA;
            }
            bf16x8 ph, pl;
#pragma unroll
            for (int i2 = 0; i2 < 4; ++i2) {
                reinterpret_cast<unsigned*>(&ph)[i2] = __byte_perm(w0[2*i2], w0[2*i2+1], 0x7632);
                reinterpret_cast<unsigned*>(&pl)[i2] = __byte_perm(w0[2*i2], w0[2*i2+1], 0x5410);
            }
#pragma unroll
            for (int dt = 0; dt < 4; ++dt) {
                int drow = (dt << 4) + qcol;
                bf16x8 ah = *reinterpret_cast<const bf16x8*>(&sm.b.vh[drow][(kb2 << 5) + (g4 << 3)]);
                bf16x8 al = *reinterpret_cast<const bf16x8*>(&sm.b.vl[drow][(kb2 << 5) + (g4 << 3)]);
                oacc[dt] = __builtin_amdgcn_mfma_f32_16x16x32_bf16(ah, ph, oacc[dt], 0, 0, 0);
                oacc[dt] = __builtin_amdgcn_mfma_f32_16x16x32_bf16(al, ph, oacc[dt], 0, 0, 0);
                oacc[dt] = __builtin_amdgcn_mfma_f32_16x16x32_bf16(ah, pl, oacc[dt], 0, 0, 0);
            }
        }
        __syncthreads();   // all LDS reads done before next chunk's staging
    }

    // ---- epilogue: O^T lane holds d = dt*16 + g4*4 + r for query q_loc ----
    float invl = 1.0f / l_r;
    float dsum = 0.0f;
    float* orow = o_io + (size_t)(rowbase + (t << 6) + q_loc) * DIMS + col0;
#pragma unroll
    for (int dt = 0; dt < 4; ++dt) {
        float4 ov = make_float4(oacc[dt][0] * invl, oacc[dt][1] * invl,
                                oacc[dt][2] * invl, oacc[dt][3] * invl);
        float* addr = orow + (dt << 4) + (g4 << 2);
        if (DIFF) {
            float4 pv4 = ld4(addr);
            dsum += fabsf(ov.x - pv4.x) + fabsf(ov.y - pv4.y)
                  + fabsf(ov.z - pv4.z) + fabsf(ov.w - pv4.w);
        }
        st4(addr, ov);
    }
    if (DIFF) {
        float s = wave_sum64(dsum);
        if (lane == 0) dred[wv] = s;
        __syncthreads();
        if (tid == 0) {
            double tot = (double)(dred[0] + dred[1] + dred[2] + dred[3]);
            unsigned long long q = (unsigned long long)(tot * FIXSCALE + 0.5);
            atomicAdd(&diff_acc[w], q);
        }
    }
}

// -------- qacc[u,:] += scramble(o)[u,:]  (torch q_cur += iter_out) -----------
__global__ __launch_bounds__(256)
void scatter_add_kernel(float* __restrict__ qacc, const float* __restrict__ o) {
    size_t gid = (size_t)blockIdx.x * 256 + threadIdx.x;
    size_t flat = gid << 2;
    int uu = (int)(flat >> 6);
    int col = (int)(flat & 63);
    int r = uu >> 4, h = uu & 15;
    int s = r & 511;
    int rb = r - s;
    size_t src = ((size_t)(rb + h * 32 + (s >> 4)) << 10)
               + (size_t)((s & 15) << 6) + col;
    float4 a = ld4(qacc + flat);
    float4 bv = ld4(o + src);
    st4(qacc + flat, make_float4(a.x + bv.x, a.y + bv.y, a.z + bv.z, a.w + bv.w));
}

__global__ void init_ctrl_kernel(unsigned long long* __restrict__ dacc,
                                 int* __restrict__ conv) {
    int i = threadIdx.x;
    if (i < 8) { dacc[i] = 0ULL; conv[i] = 0; }
}

__global__ void conv_from_acc_kernel(const unsigned long long* __restrict__ dacc,
                                     int* __restrict__ conv) {
    int w = threadIdx.x;
    if (w < 8) {
        float mean = (float)((double)dacc[w] * (1.0 / (FIXSCALE * 2097152.0)));
        conv[w] = (mean < 0.01f + 0.1f * mean) ? 1 : 0;
    }
}

// -------- unscramble src into preout [B,S,DIMS] ------------------------------
__global__ __launch_bounds__(256)
void unscramble_kernel(const float* __restrict__ src, float* __restrict__ outp) {
    size_t gid = (size_t)blockIdx.x * 256 + threadIdx.x;
    size_t flat = gid << 2;
    int r = (int)(flat >> 10);
    int e = (int)(flat & 1023);
    int h2 = e >> 6, d2 = e & 63;
    int s2 = r & 511;
    int rb = r - s2;
    size_t sidx = ((size_t)(rb + h2 * 32 + (s2 >> 4)) << 10) + (size_t)((s2 & 15) << 6) + d2;
    st4(outp + flat, ld4(src + sidx));
}

extern "C" void kernel_launch(void* const* d_in, const int* in_sizes, int n_in,
                              void* d_out, int out_size, void* d_ws, size_t ws_size,
                              hipStream_t stream) {
    (void)in_sizes; (void)n_in; (void)out_size; (void)ws_size;
    const float* x   = (const float*)d_in[0];
    const float* Wq  = (const float*)d_in[1];
    const float* bq  = (const float*)d_in[2];
    const float* Wk  = (const float*)d_in[3];
    const float* Wv  = (const float*)d_in[4];
    const float* bv  = (const float*)d_in[5];
    const float* Wo  = (const float*)d_in[6];
    const float* bo  = (const float*)d_in[7];
    const float* lna = (const float*)d_in[8];
    const float* lnb = (const float*)d_in[9];
    const float* lqw = (const float*)d_in[10];
    const float* lqb = (const float*)d_in[11];
    const float* lkw = (const float*)d_in[12];
    const float* lkb = (const float*)d_in[13];
    const float* lvw = (const float*)d_in[14];
    const float* lvb = (const float*)d_in[15];

    // ws: [4 KiB ctrl][R1 qacc][R2 xn->khl->preout][R3 v->o] = 192 MiB + 4 KiB
    const size_t BUF = (size_t)NROWS * DIMS;      // 16M elements
    unsigned long long* dacc = (unsigned long long*)d_ws;
    int* conv = (int*)(dacc + 8);
    float* R1 = (float*)((char*)d_ws + 4096);
    float* R2 = R1 + BUF;
    float* R3 = R2 + BUF;
    float* E  = (float*)d_out;     // k f32 -> vthl plane -> final out

    const float scale = 0.35355339059327373f;     // 64^-0.25

    // 1. xn = LN(x) -> R2
    ln1024_kernel<<<NROWS, 256, 0, stream>>>(x, lna, R2);

    // 2. q,k,v GEMMs (xn in R2; k lands in d_out temporarily)
    dim3 gg(NROWS / 128, DIMS / 128);
    gemm_nt_kernel<<<gg, 256, 0, stream>>>(R2, Wq, bq,      R1, NROWS, DIMS, DIMS, scale, 1);
    gemm_nt_kernel<<<gg, 256, 0, stream>>>(R2, Wk, nullptr, E,  NROWS, DIMS, DIMS, scale, 0);
    gemm_nt_kernel<<<gg, 256, 0, stream>>>(R2, Wv, bv,      R3, NROWS, DIMS, DIMS, 1.0f, 1);

    // 3. per-head LN on q (R1), k (E)
    headln_kernel<<<NUNITS / 4, 256, 0, stream>>>(R1, E, lnb);

    // 4. kp plane (xn dead): E -> R2 ; vt plane (k dead): R3 -> E
    proj64_khl_kernel<<<NUNITS / 64, 256, 0, stream>>>(E, lkw, lkb, lnb, (unsigned*)R2);
    proj64_vthl_kernel<<<NUNITS / 64, 256, 0, stream>>>(R3, lvw, lvb, (unsigned*)E);

    // 5. control init
    init_ctrl_kernel<<<1, 64, 0, stream>>>(dacc, conv);

    const unsigned* KHL = (const unsigned*)R2;
    const unsigned* VTHL = (const unsigned*)E;

    // 6. it 0: o0 -> R3 (v f32 dead)
    attn_mfma_kernel<0, 0><<<512 * 8, 256, 0, stream>>>(R1, KHL, VTHL, R3, lqw, lqb, lnb, dacc, conv);
    // 7. qacc += scr(o0)
    scatter_add_kernel<<<NROWS * DIMS / 4 / 256, 256, 0, stream>>>(R1, R3);
    // 8. it 1: o1 -> R3 in place, fused per-window diff vs o0
    attn_mfma_kernel<1, 0><<<512 * 8, 256, 0, stream>>>(R1, KHL, VTHL, R3, lqw, lqb, lnb, dacc, conv);
    // 9. conv flags
    conv_from_acc_kernel<<<1, 64, 0, stream>>>(dacc, conv);
    // 10. qacc += scr(o1)
    scatter_add_kernel<<<NROWS * DIMS / 4 / 256, 256, 0, stream>>>(R1, R3);
    // 11. it 2: o2 -> R3, skipped for converged windows (keeps o1)
    attn_mfma_kernel<0, 1><<<512 * 8, 256, 0, stream>>>(R1, KHL, VTHL, R3, lqw, lqb, lnb, dacc, conv);

    // 12. preout = unscramble(R3) -> R2 (khl dead)
    unscramble_kernel<<<NROWS * DIMS / 4 / 256, 256, 0, stream>>>(R3, R2);
    // 13. out = preout @ Wo^T + bo -> d_out (vthl dead)
    gemm_nt_kernel<<<gg, 256, 0, stream>>>(R2, Wo, bo, (float*)d_out, NROWS, DIMS, DIMS, 1.0f, 1);
}

// Round 5
// 1790.348 us; speedup vs baseline: 3.0138x; 1.7647x over previous
//
#include <hip/hip_runtime.h>
#include <math.h>

// Problem constants (from reference)
#define DIMS   1024
#define NHEAD  16
#define HD     64
#define WIN    512
#define CTX    4096
#define NBATCH 4
#define NROWS  (NBATCH*CTX)        // 16384 total sequence rows
#define NUNITS (NROWS*NHEAD)       // 262144 (row,head) units
#define LNEPS  1e-5f
#define FIXSCALE 16777216.0        // 2^24 fixed-point for deterministic diff

typedef __attribute__((ext_vector_type(8))) short bf16x8;   // 8 bf16 (4 VGPR)
typedef __attribute__((ext_vector_type(4))) float f32x4;    // MFMA C/D

__device__ __forceinline__ float4 ld4(const float* p) { return *reinterpret_cast<const float4*>(p); }
__device__ __forceinline__ void st4(float* p, float4 v) { *reinterpret_cast<float4*>(p) = v; }

__device__ __forceinline__ float wave_sum64(float v) {
#pragma unroll
    for (int off = 32; off; off >>= 1) v += __shfl_xor(v, off, 64);
    return v;
}
__device__ __forceinline__ float grp16_sum(float v) {
    v += __shfl_xor(v, 1, 64);
    v += __shfl_xor(v, 2, 64);
    v += __shfl_xor(v, 4, 64);
    v += __shfl_xor(v, 8, 64);
    return v;
}

// round-to-nearest-even bf16 of x, packed split: (hi<<16)|lo with hi+lo ~= x (err ~2^-17)
__device__ __forceinline__ unsigned bf16_rn_bits(float x) {
    unsigned u = __float_as_uint(x);
    return (u + 0x7fffu + ((u >> 16) & 1u)) >> 16;
}
__device__ __forceinline__ unsigned pack_hl(float x) {
    unsigned h = bf16_rn_bits(x);
    float hf = __uint_as_float(h << 16);
    unsigned l = bf16_rn_bits(x - hf);
    return (h << 16) | (l & 0xffffu);
}

// XOR-swizzled byte offset into a [rows][64] short LDS plane (stride 128 B)
__device__ __forceinline__ int swzo(int row, int kbyte) {
    return ((row << 7) + kbyte) ^ ((row & 7) << 4);
}

// -------- LayerNorm over D=1024 (row-wise), PACKED hi/lo output --------------
__global__ __launch_bounds__(256)
void ln1024_pack_kernel(const float* __restrict__ x, const float* __restrict__ w,
                        unsigned* __restrict__ outp) {
    int r = blockIdx.x;
    int tid = threadIdx.x;
    const float* xr = x + (size_t)r * DIMS;
    float4 v = ld4(xr + (tid << 2));
    __shared__ float red[8];
    float s = wave_sum64(v.x + v.y + v.z + v.w);
    int wv = tid >> 6, lane = tid & 63;
    if (lane == 0) red[wv] = s;
    __syncthreads();
    float mean = (red[0] + red[1] + red[2] + red[3]) * (1.0f / DIMS);
    float dx = v.x - mean, dy = v.y - mean, dz = v.z - mean, dw = v.w - mean;
    float ss = wave_sum64(dx*dx + dy*dy + dz*dz + dw*dw);
    if (lane == 0) red[4 + wv] = ss;
    __syncthreads();
    float inv = rsqrtf((red[4] + red[5] + red[6] + red[7]) * (1.0f / DIMS) + LNEPS);
    float4 wv4 = ld4(w + (tid << 2));
    uint4 pk;
    pk.x = pack_hl(dx * inv * wv4.x);
    pk.y = pack_hl(dy * inv * wv4.y);
    pk.z = pack_hl(dz * inv * wv4.z);
    pk.w = pack_hl(dw * inv * wv4.w);
    *reinterpret_cast<uint4*>(outp + (size_t)r * DIMS + (tid << 2)) = pk;
}

// -------- bf16 hi/lo 3-term MFMA GEMM ----------------------------------------
// C[m,n] = alpha*(sum_k A[m,k]*W[n,k] + bias[n]); A packed-hl u32 [M,1024],
// W f32 [N,1024] split on the fly. Tile 128x128x64, 256 thr (4 waves of 64x64).
__global__ __launch_bounds__(256, 2)
void gemm_hl_kernel(const unsigned* __restrict__ Ahl, const float* __restrict__ W,
                    const float* __restrict__ bias, float* __restrict__ Cm,
                    float alpha, int has_bias) {
    __shared__ short Ah[128 * 64], Al[128 * 64], Wh[128 * 64], Wl[128 * 64]; // 64 KiB
    int tid = threadIdx.x;
    int wid = tid >> 6, lane = tid & 63;
    int wm = (wid >> 1) << 6, wn = (wid & 1) << 6;
    int g4 = lane >> 4, l16 = lane & 15;
    int m0 = blockIdx.x << 7, n0 = blockIdx.y << 7;

    f32x4 acc[4][4] = {};

    int orow[4], okb[4];   // staging octos: row, k-byte offset (8 shorts = 16 B)
#pragma unroll
    for (int j = 0; j < 4; ++j) {
        int oc = tid + (j << 8);
        orow[j] = oc >> 3;
        okb[j] = (oc & 7) << 4;
    }

    for (int k0 = 0; k0 < 1024; k0 += 64) {
        uint4 a0[4], a1[4];
        float4 w0[4], w1[4];
#pragma unroll
        for (int j = 0; j < 4; ++j) {
            const unsigned* ap = Ahl + (size_t)(m0 + orow[j]) * 1024 + k0 + (okb[j] >> 1);
            a0[j] = *reinterpret_cast<const uint4*>(ap);
            a1[j] = *reinterpret_cast<const uint4*>(ap + 4);
            const float* wp = W + (size_t)(n0 + orow[j]) * 1024 + k0 + (okb[j] >> 1);
            w0[j] = *reinterpret_cast<const float4*>(wp);
            w1[j] = *reinterpret_cast<const float4*>(wp + 4);
        }
        __syncthreads();   // prior iteration's fragment reads complete
#pragma unroll
        for (int j = 0; j < 4; ++j) {
            int off = swzo(orow[j], okb[j]);
            uint4 hi, lo;
            hi.x = __byte_perm(a0[j].x, a0[j].y, 0x7632);
            hi.y = __byte_perm(a0[j].z, a0[j].w, 0x7632);
            hi.z = __byte_perm(a1[j].x, a1[j].y, 0x7632);
            hi.w = __byte_perm(a1[j].z, a1[j].w, 0x7632);
            lo.x = __byte_perm(a0[j].x, a0[j].y, 0x5410);
            lo.y = __byte_perm(a0[j].z, a0[j].w, 0x5410);
            lo.z = __byte_perm(a1[j].x, a1[j].y, 0x5410);
            lo.w = __byte_perm(a1[j].z, a1[j].w, 0x5410);
            *reinterpret_cast<uint4*>(reinterpret_cast<char*>(Ah) + off) = hi;
            *reinterpret_cast<uint4*>(reinterpret_cast<char*>(Al) + off) = lo;

            float xs[8];
            *reinterpret_cast<float4*>(&xs[0]) = w0[j];
            *reinterpret_cast<float4*>(&xs[4]) = w1[j];
            uint4 hw, lw;
            unsigned* hwp = &hw.x;
            unsigned* lwp = &lw.x;
#pragma unroll
            for (int p = 0; p < 4; ++p) {
                unsigned u0 = __float_as_uint(xs[2*p]);
                unsigned u1 = __float_as_uint(xs[2*p + 1]);
                unsigned h0 = (u0 + 0x8000u) >> 16;   // round-half-up bf16
                unsigned h1 = (u1 + 0x8000u) >> 16;
                float l0 = xs[2*p]     - __uint_as_float(h0 << 16);
                float l1 = xs[2*p + 1] - __uint_as_float(h1 << 16);
                unsigned lb0 = (__float_as_uint(l0) + 0x8000u) >> 16;
                unsigned lb1 = (__float_as_uint(l1) + 0x8000u) >> 16;
                hwp[p] = h0 | (h1 << 16);
                lwp[p] = lb0 | (lb1 << 16);
            }
            *reinterpret_cast<uint4*>(reinterpret_cast<char*>(Wh) + off) = hw;
            *reinterpret_cast<uint4*>(reinterpret_cast<char*>(Wl) + off) = lw;
        }
        __syncthreads();

#pragma unroll
        for (int kk = 0; kk < 2; ++kk) {
            bf16x8 afh[4], afl[4], wfh[4], wfl[4];
#pragma unroll
            for (int mt = 0; mt < 4; ++mt) {
                int row = wm + (mt << 4) + l16;
                int off = ((row << 7) + (kk << 6) + (g4 << 4)) ^ ((row & 7) << 4);
                afh[mt] = *reinterpret_cast<const bf16x8*>(reinterpret_cast<const char*>(Ah) + off);
                afl[mt] = *reinterpret_cast<const bf16x8*>(reinterpret_cast<const char*>(Al) + off);
            }
#pragma unroll
            for (int nt = 0; nt < 4; ++nt) {
                int row = wn + (nt << 4) + l16;
                int off = ((row << 7) + (kk << 6) + (g4 << 4)) ^ ((row & 7) << 4);
                wfh[nt] = *reinterpret_cast<const bf16x8*>(reinterpret_cast<const char*>(Wh) + off);
                wfl[nt] = *reinterpret_cast<const bf16x8*>(reinterpret_cast<const char*>(Wl) + off);
            }
#pragma unroll
            for (int mt = 0; mt < 4; ++mt)
#pragma unroll
                for (int nt = 0; nt < 4; ++nt) {
                    acc[mt][nt] = __builtin_amdgcn_mfma_f32_16x16x32_bf16(afh[mt], wfh[nt], acc[mt][nt], 0, 0, 0);
                    acc[mt][nt] = __builtin_amdgcn_mfma_f32_16x16x32_bf16(afl[mt], wfh[nt], acc[mt][nt], 0, 0, 0);
                    acc[mt][nt] = __builtin_amdgcn_mfma_f32_16x16x32_bf16(afh[mt], wfl[nt], acc[mt][nt], 0, 0, 0);
                }
        }
    }

    // epilogue: D[row=(g4*4+r)][col=l16] per 16x16 tile
#pragma unroll
    for (int mt = 0; mt < 4; ++mt)
#pragma unroll
        for (int nt = 0; nt < 4; ++nt) {
            int col = n0 + wn + (nt << 4) + l16;
            float bb = has_bias ? bias[col] : 0.0f;
#pragma unroll
            for (int r = 0; r < 4; ++r) {
                int row = m0 + wm + (mt << 4) + (g4 << 2) + r;
                Cm[(size_t)row * DIMS + col] = alpha * (acc[mt][nt][r] + bb);
            }
        }
}

// -------- per-(row,head) LayerNorm over d=64, in place on q and k ------------
__global__ __launch_bounds__(256)
void headln_kernel(float* __restrict__ q, float* __restrict__ k,
                   const float* __restrict__ lnw) {
    int gw = (blockIdx.x << 2) + (threadIdx.x >> 6);
    int lane = threadIdx.x & 63;
    size_t idx = ((size_t)gw << 6) + lane;
    float wgt = lnw[lane];
    {
        float v = q[idx];
        float mean = wave_sum64(v) * (1.0f / 64.0f);
        float d = v - mean;
        float var = wave_sum64(d * d) * (1.0f / 64.0f);
        q[idx] = d * rsqrtf(var + LNEPS) * wgt;
    }
    {
        float v = k[idx];
        float mean = wave_sum64(v) * (1.0f / 64.0f);
        float d = v - mean;
        float var = wave_sum64(d * d) * (1.0f / 64.0f);
        k[idx] = d * rsqrtf(var + LNEPS) * wgt;
    }
}

// -------- kp projection + LN + hi/lo split -> packed K plane -----------------
// K plane layout: u32 khl[unit*512 + s][64] where unit = (b*8+w)*16+h
__global__ __launch_bounds__(256)
void proj64_khl_kernel(const float* __restrict__ inp, const float* __restrict__ W,
                       const float* __restrict__ Wb, const float* __restrict__ lnw,
                       unsigned* __restrict__ plane) {
    int u0 = blockIdx.x << 6;
    __shared__ float As[64][68];
    __shared__ float Bs[64][68];
    int tid = threadIdx.x;
    for (int e = tid; e < 4096; e += 256) Bs[e & 63][e >> 6] = W[e];
    for (int e = tid; e < 1024; e += 256) {
        int row = e >> 4;
        int col = (e & 15) << 2;
        float4 v = ld4(inp + ((size_t)(u0 + row) << 6) + col);
        As[col + 0][row] = v.x; As[col + 1][row] = v.y;
        As[col + 2][row] = v.z; As[col + 3][row] = v.w;
    }
    __syncthreads();
    int tm = tid >> 4, tn = tid & 15;
    float acc[4][4] = {};
#pragma unroll
    for (int k = 0; k < 64; ++k) {
        float4 av = ld4(&As[k][tm << 2]);
        float4 bv = ld4(&Bs[k][tn << 2]);
        float aa[4] = {av.x, av.y, av.z, av.w};
        float bb[4] = {bv.x, bv.y, bv.z, bv.w};
#pragma unroll
        for (int mm = 0; mm < 4; ++mm)
#pragma unroll
            for (int nn = 0; nn < 4; ++nn)
                acc[mm][nn] = fmaf(aa[mm], bb[nn], acc[mm][nn]);
    }
    float bb4[4] = {Wb[(tn << 2) + 0], Wb[(tn << 2) + 1], Wb[(tn << 2) + 2], Wb[(tn << 2) + 3]};
    float lw4[4] = {lnw[(tn << 2) + 0], lnw[(tn << 2) + 1], lnw[(tn << 2) + 2], lnw[(tn << 2) + 3]};
#pragma unroll
    for (int mm = 0; mm < 4; ++mm) {
        float o0 = acc[mm][0] + bb4[0], o1 = acc[mm][1] + bb4[1];
        float o2 = acc[mm][2] + bb4[2], o3 = acc[mm][3] + bb4[3];
        float mean = grp16_sum(o0 + o1 + o2 + o3) * (1.0f / 64.0f);
        float d0 = o0 - mean, d1 = o1 - mean, d2 = o2 - mean, d3 = o3 - mean;
        float var = grp16_sum(d0*d0 + d1*d1 + d2*d2 + d3*d3) * (1.0f / 64.0f);
        float inv = rsqrtf(var + LNEPS);
        o0 = d0 * inv * lw4[0]; o1 = d1 * inv * lw4[1];
        o2 = d2 * inv * lw4[2]; o3 = d3 * inv * lw4[3];
        int u_p = u0 + (tm << 2) + mm;
        int r = u_p >> 4, h = u_p & 15;
        int s = r & 511;
        int ua = ((r >> 9) << 4) + h;
        size_t punit = (size_t)ua * 512 + s;
        uint4 pk;
        pk.x = pack_hl(o0); pk.y = pack_hl(o1); pk.z = pack_hl(o2); pk.w = pack_hl(o3);
        *reinterpret_cast<uint4*>(plane + (punit << 6) + (tn << 2)) = pk;
    }
}

// -------- vp projection + hi/lo split -> packed transposed V plane -----------
// VT plane layout: u32 vthl[(unit*8 + chunk)*64 + d][64 j]
__global__ __launch_bounds__(256)
void proj64_vthl_kernel(const float* __restrict__ inp, const float* __restrict__ W,
                        const float* __restrict__ Wb, unsigned* __restrict__ plane) {
    int u0 = blockIdx.x << 6;
    __shared__ float As[64][68];
    __shared__ float Bs[64][68];
    int tid = threadIdx.x;
    for (int e = tid; e < 4096; e += 256) Bs[e & 63][e >> 6] = W[e];
    for (int e = tid; e < 1024; e += 256) {
        int row = e >> 4;
        int col = (e & 15) << 2;
        float4 v = ld4(inp + ((size_t)(u0 + row) << 6) + col);
        As[col + 0][row] = v.x; As[col + 1][row] = v.y;
        As[col + 2][row] = v.z; As[col + 3][row] = v.w;
    }
    __syncthreads();
    int tm = tid >> 4, tn = tid & 15;
    float acc[4][4] = {};
#pragma unroll
    for (int k = 0; k < 64; ++k) {
        float4 av = ld4(&As[k][tm << 2]);
        float4 bv = ld4(&Bs[k][tn << 2]);
        float aa[4] = {av.x, av.y, av.z, av.w};
        float bb[4] = {bv.x, bv.y, bv.z, bv.w};
#pragma unroll
        for (int mm = 0; mm < 4; ++mm)
#pragma unroll
            for (int nn = 0; nn < 4; ++nn)
                acc[mm][nn] = fmaf(aa[mm], bb[nn], acc[mm][nn]);
    }
    float bb4[4] = {Wb[(tn << 2) + 0], Wb[(tn << 2) + 1], Wb[(tn << 2) + 2], Wb[(tn << 2) + 3]};
#pragma unroll
    for (int mm = 0; mm < 4; ++mm) {
        int u_p = u0 + (tm << 2) + mm;
        int r = u_p >> 4, h = u_p & 15;
        int s = r & 511;
        int ua = ((r >> 9) << 4) + h;
        size_t base = ((size_t)(ua * 8 + (s >> 6)) << 12) + (s & 63);
#pragma unroll
        for (int nn = 0; nn < 4; ++nn) {
            int d = (tn << 2) + nn;
            plane[base + ((size_t)d << 6)] = pack_hl(acc[mm][nn] + bb4[nn]);
        }
    }
}

// -------- fused MFMA attention (unchanged from round 4) ----------------------
template<int DIFF, int USE_CONV>
__global__ __launch_bounds__(256)
void attn_mfma_kernel(const float* __restrict__ qacc, const unsigned* __restrict__ khl,
                      const unsigned* __restrict__ vthl, float* __restrict__ o_io,
                      const float* __restrict__ lqw, const float* __restrict__ lqb,
                      const float* __restrict__ lnw,
                      unsigned long long* __restrict__ diff_acc,
                      const int* __restrict__ conv) {
    __shared__ union {
        struct { float lq[64][68]; float qt[64][68]; float qs[64][68]; } a;  // phase A
        struct { short kh[64][72], kl[64][72], vh[64][72], vl[64][72]; } b;  // chunk loop
    } sm;
    __shared__ float dred[4];

    int blk = blockIdx.x;
    int t = blk & 7;
    int u = blk >> 3;
    int h = u & 15;
    int w = (u >> 4) & 7;
    int b = u >> 7;
    if (USE_CONV && conv[w]) return;
    int rowbase = b * CTX + w * WIN;
    int col0 = h * HD;
    int tid = threadIdx.x;
    int tm = tid >> 4, tn = tid & 15;
    int wv = tid >> 6;
    int lane = tid & 63;
    int g4 = lane >> 4;
    int qcol = lane & 15;
    int q_loc = (wv << 4) + qcol;

    // ---- phase A: qp = LN(qacc @ lqw^T + lqb), fp32, -> sm.a.qs[d][m] ----
    for (int e = tid; e < 4096; e += 256) sm.a.lq[e & 63][e >> 6] = lqw[e];
    for (int e = tid; e < 1024; e += 256) {
        int row = e >> 4;
        int col = (e & 15) << 2;
        float4 v = ld4(qacc + (size_t)(rowbase + (t << 6) + row) * DIMS + col0 + col);
        sm.a.qt[col + 0][row] = v.x; sm.a.qt[col + 1][row] = v.y;
        sm.a.qt[col + 2][row] = v.z; sm.a.qt[col + 3][row] = v.w;
    }
    __syncthreads();
    {
        float acc[4][4] = {};
#pragma unroll
        for (int k = 0; k < 64; ++k) {
            float4 av = ld4(&sm.a.qt[k][tm << 2]);
            float4 bv = ld4(&sm.a.lq[k][tn << 2]);
            float aa[4] = {av.x, av.y, av.z, av.w};
            float bb[4] = {bv.x, bv.y, bv.z, bv.w};
#pragma unroll
            for (int mm = 0; mm < 4; ++mm)
#pragma unroll
                for (int nn = 0; nn < 4; ++nn)
                    acc[mm][nn] = fmaf(aa[mm], bb[nn], acc[mm][nn]);
        }
        float bb4[4] = {lqb[(tn << 2) + 0], lqb[(tn << 2) + 1],
                        lqb[(tn << 2) + 2], lqb[(tn << 2) + 3]};
        float lw4[4] = {lnw[(tn << 2) + 0], lnw[(tn << 2) + 1],
                        lnw[(tn << 2) + 2], lnw[(tn << 2) + 3]};
#pragma unroll
        for (int mm = 0; mm < 4; ++mm) {
            float o0 = acc[mm][0] + bb4[0], o1 = acc[mm][1] + bb4[1];
            float o2 = acc[mm][2] + bb4[2], o3 = acc[mm][3] + bb4[3];
            float mean = grp16_sum(o0 + o1 + o2 + o3) * (1.0f / 64.0f);
            float d0 = o0 - mean, d1 = o1 - mean, d2 = o2 - mean, d3 = o3 - mean;
            float var = grp16_sum(d0*d0 + d1*d1 + d2*d2 + d3*d3) * (1.0f / 64.0f);
            float inv = rsqrtf(var + LNEPS);
            int m = (tm << 2) + mm;
            sm.a.qs[(tn << 2) + 0][m] = d0 * inv * lw4[0];
            sm.a.qs[(tn << 2) + 1][m] = d1 * inv * lw4[1];
            sm.a.qs[(tn << 2) + 2][m] = d2 * inv * lw4[2];
            sm.a.qs[(tn << 2) + 3][m] = d3 * inv * lw4[3];
        }
    }
    __syncthreads();

    // ---- build Q B-fragments (hi/lo) in registers ----
    bf16x8 qfh[2], qfl[2];
#pragma unroll
    for (int kb = 0; kb < 2; ++kb)
#pragma unroll
        for (int i = 0; i < 8; ++i) {
            float v = sm.a.qs[(kb << 5) + (g4 << 3) + i][q_loc];
            unsigned hb = bf16_rn_bits(v);
            float hf = __uint_as_float(hb << 16);
            unsigned lb = bf16_rn_bits(v - hf);
            qfh[kb][i] = (short)hb;
            qfl[kb][i] = (short)lb;
        }
    __syncthreads();

    // ---- flash loop ----
    float m_r = -INFINITY, l_r = 0.0f;
    f32x4 oacc[4] = {{0,0,0,0},{0,0,0,0},{0,0,0,0},{0,0,0,0}};
    const unsigned* kbase = khl + (((size_t)u * 512) << 6);
    const unsigned* vbase = vthl + (((size_t)u * 8) << 12);

    for (int c = 0; c <= t; ++c) {
        const unsigned* ksrc = kbase + (((size_t)c * 64) << 6);
        const unsigned* vsrc = vbase + (((size_t)c) << 12);
#pragma unroll
        for (int rr = 0; rr < 4; ++rr) {
            int row = (wv << 4) + (rr << 2) + g4;
            uint4 pk = *reinterpret_cast<const uint4*>(ksrc + ((size_t)row << 6) + (qcol << 2));
            unsigned* khp = reinterpret_cast<unsigned*>(&sm.b.kh[row][qcol << 2]);
            khp[0] = __byte_perm(pk.x, pk.y, 0x7632);
            khp[1] = __byte_perm(pk.z, pk.w, 0x7632);
            unsigned* klp = reinterpret_cast<unsigned*>(&sm.b.kl[row][qcol << 2]);
            klp[0] = __byte_perm(pk.x, pk.y, 0x5410);
            klp[1] = __byte_perm(pk.z, pk.w, 0x5410);
            uint4 pv = *reinterpret_cast<const uint4*>(vsrc + ((size_t)row << 6) + (qcol << 2));
            unsigned* vhp = reinterpret_cast<unsigned*>(&sm.b.vh[row][qcol << 2]);
            vhp[0] = __byte_perm(pv.x, pv.y, 0x7632);
            vhp[1] = __byte_perm(pv.z, pv.w, 0x7632);
            unsigned* vlp = reinterpret_cast<unsigned*>(&sm.b.vl[row][qcol << 2]);
            vlp[0] = __byte_perm(pv.x, pv.y, 0x5410);
            vlp[1] = __byte_perm(pv.z, pv.w, 0x5410);
        }
        __syncthreads();

        f32x4 sacc[4] = {{0,0,0,0},{0,0,0,0},{0,0,0,0},{0,0,0,0}};
#pragma unroll
        for (int jt = 0; jt < 4; ++jt) {
            int jrow = (jt << 4) + qcol;
#pragma unroll
            for (int kb = 0; kb < 2; ++kb) {
                bf16x8 ah = *reinterpret_cast<const bf16x8*>(&sm.b.kh[jrow][(kb << 5) + (g4 << 3)]);
                bf16x8 al = *reinterpret_cast<const bf16x8*>(&sm.b.kl[jrow][(kb << 5) + (g4 << 3)]);
                sacc[jt] = __builtin_amdgcn_mfma_f32_16x16x32_bf16(ah, qfh[kb], sacc[jt], 0, 0, 0);
                sacc[jt] = __builtin_amdgcn_mfma_f32_16x16x32_bf16(al, qfh[kb], sacc[jt], 0, 0, 0);
                sacc[jt] = __builtin_amdgcn_mfma_f32_16x16x32_bf16(ah, qfl[kb], sacc[jt], 0, 0, 0);
            }
        }

        float sv[16];
        float mx = -3.0e38f;
#pragma unroll
        for (int jt = 0; jt < 4; ++jt)
#pragma unroll
            for (int r = 0; r < 4; ++r) {
                float s = sacc[jt][r] * 0.125f;
                if (c == t) {
                    int j_loc = (jt << 4) + (g4 << 2) + r;
                    if (j_loc > q_loc) s = -3.0e38f;
                }
                sv[(jt << 2) + r] = s;
                mx = fmaxf(mx, s);
            }
        mx = fmaxf(mx, __shfl_xor(mx, 16, 64));
        mx = fmaxf(mx, __shfl_xor(mx, 32, 64));
        float mnew = fmaxf(m_r, mx);
        float ps = 0.0f;
        unsigned pu[16];
#pragma unroll
        for (int e = 0; e < 16; ++e) {
            float p = __expf(sv[e] - mnew);
            ps += p;
            pu[e] = pack_hl(p);
        }
        ps += __shfl_xor(ps, 16, 64);
        ps += __shfl_xor(ps, 32, 64);
        float ef = __expf(m_r - mnew);
        l_r = l_r * ef + ps;
        m_r = mnew;
#pragma unroll
        for (int dt = 0; dt < 4; ++dt) oacc[dt] *= ef;

#pragma unroll
        for (int kb2 = 0; kb2 < 2; ++kb2) {
            unsigned w0[8];
#pragma unroll
            for (int i = 0; i < 8; ++i) {
                int src = ((((g4 & 1) << 1) + (i >> 2)) << 4) | qcol;
                unsigned vA = __shfl(pu[((kb2 << 1) + 0) * 4 + (i & 3)], src, 64);
                unsigned vB = __shfl(pu[((kb2 << 1) + 1) * 4 + (i & 3)], src, 64);
                w0[i] = (g4 >> 1) ? vB : vA;
            }
            bf16x8 ph, pl;
#pragma unroll
            for (int i2 = 0; i2 < 4; ++i2) {
                reinterpret_cast<unsigned*>(&ph)[i2] = __byte_perm(w0[2*i2], w0[2*i2+1], 0x7632);
                reinterpret_cast<unsigned*>(&pl)[i2] = __byte_perm(w0[2*i2], w0[2*i2+1], 0x5410);
            }
#pragma unroll
            for (int dt = 0; dt < 4; ++dt) {
                int drow = (dt << 4) + qcol;
                bf16x8 ah = *reinterpret_cast<const bf16x8*>(&sm.b.vh[drow][(kb2 << 5) + (g4 << 3)]);
                bf16x8 al = *reinterpret_cast<const bf16x8*>(&sm.b.vl[drow][(kb2 << 5) + (g4 << 3)]);
                oacc[dt] = __builtin_amdgcn_mfma_f32_16x16x32_bf16(ah, ph, oacc[dt], 0, 0, 0);
                oacc[dt] = __builtin_amdgcn_mfma_f32_16x16x32_bf16(al, ph, oacc[dt], 0, 0, 0);
                oacc[dt] = __builtin_amdgcn_mfma_f32_16x16x32_bf16(ah, pl, oacc[dt], 0, 0, 0);
            }
        }
        __syncthreads();
    }

    float invl = 1.0f / l_r;
    float dsum = 0.0f;
    float* orow = o_io + (size_t)(rowbase + (t << 6) + q_loc) * DIMS + col0;
#pragma unroll
    for (int dt = 0; dt < 4; ++dt) {
        float4 ov = make_float4(oacc[dt][0] * invl, oacc[dt][1] * invl,
                                oacc[dt][2] * invl, oacc[dt][3] * invl);
        float* addr = orow + (dt << 4) + (g4 << 2);
        if (DIFF) {
            float4 pv4 = ld4(addr);
            dsum += fabsf(ov.x - pv4.x) + fabsf(ov.y - pv4.y)
                  + fabsf(ov.z - pv4.z) + fabsf(ov.w - pv4.w);
        }
        st4(addr, ov);
    }
    if (DIFF) {
        float s = wave_sum64(dsum);
        if (lane == 0) dred[wv] = s;
        __syncthreads();
        if (tid == 0) {
            double tot = (double)(dred[0] + dred[1] + dred[2] + dred[3]);
            unsigned long long q = (unsigned long long)(tot * FIXSCALE + 0.5);
            atomicAdd(&diff_acc[w], q);
        }
    }
}

// -------- qacc[u,:] += scramble(o)[u,:]  (torch q_cur += iter_out) -----------
__global__ __launch_bounds__(256)
void scatter_add_kernel(float* __restrict__ qacc, const float* __restrict__ o) {
    size_t gid = (size_t)blockIdx.x * 256 + threadIdx.x;
    size_t flat = gid << 2;
    int uu = (int)(flat >> 6);
    int col = (int)(flat & 63);
    int r = uu >> 4, h = uu & 15;
    int s = r & 511;
    int rb = r - s;
    size_t src = ((size_t)(rb + h * 32 + (s >> 4)) << 10)
               + (size_t)((s & 15) << 6) + col;
    float4 a = ld4(qacc + flat);
    float4 bv = ld4(o + src);
    st4(qacc + flat, make_float4(a.x + bv.x, a.y + bv.y, a.z + bv.z, a.w + bv.w));
}

__global__ void init_ctrl_kernel(unsigned long long* __restrict__ dacc,
                                 int* __restrict__ conv) {
    int i = threadIdx.x;
    if (i < 8) { dacc[i] = 0ULL; conv[i] = 0; }
}

__global__ void conv_from_acc_kernel(const unsigned long long* __restrict__ dacc,
                                     int* __restrict__ conv) {
    int w = threadIdx.x;
    if (w < 8) {
        float mean = (float)((double)dacc[w] * (1.0 / (FIXSCALE * 2097152.0)));
        conv[w] = (mean < 0.01f + 0.1f * mean) ? 1 : 0;
    }
}

// -------- unscramble src into packed-hl preout [B,S,DIMS] --------------------
__global__ __launch_bounds__(256)
void unscramble_pack_kernel(const float* __restrict__ src, unsigned* __restrict__ outp) {
    size_t gid = (size_t)blockIdx.x * 256 + threadIdx.x;
    size_t flat = gid << 2;
    int r = (int)(flat >> 10);
    int e = (int)(flat & 1023);
    int h2 = e >> 6, d2 = e & 63;
    int s2 = r & 511;
    int rb = r - s2;
    size_t sidx = ((size_t)(rb + h2 * 32 + (s2 >> 4)) << 10) + (size_t)((s2 & 15) << 6) + d2;
    float4 v = ld4(src + sidx);
    uint4 pk;
    pk.x = pack_hl(v.x); pk.y = pack_hl(v.y); pk.z = pack_hl(v.z); pk.w = pack_hl(v.w);
    *reinterpret_cast<uint4*>(outp + flat) = pk;
}

extern "C" void kernel_launch(void* const* d_in, const int* in_sizes, int n_in,
                              void* d_out, int out_size, void* d_ws, size_t ws_size,
                              hipStream_t stream) {
    (void)in_sizes; (void)n_in; (void)out_size; (void)ws_size;
    const float* x   = (const float*)d_in[0];
    const float* Wq  = (const float*)d_in[1];
    const float* bq  = (const float*)d_in[2];
    const float* Wk  = (const float*)d_in[3];
    const float* Wv  = (const float*)d_in[4];
    const float* bv  = (const float*)d_in[5];
    const float* Wo  = (const float*)d_in[6];
    const float* bo  = (const float*)d_in[7];
    const float* lna = (const float*)d_in[8];
    const float* lnb = (const float*)d_in[9];
    const float* lqw = (const float*)d_in[10];
    const float* lqb = (const float*)d_in[11];
    const float* lkw = (const float*)d_in[12];
    const float* lkb = (const float*)d_in[13];
    const float* lvw = (const float*)d_in[14];
    const float* lvb = (const float*)d_in[15];

    // ws: [4 KiB ctrl][R1 qacc][R2 xnhl->khl->preout_hl][R3 v->o] = 192 MiB + 4 KiB
    const size_t BUF = (size_t)NROWS * DIMS;      // 16M elements
    unsigned long long* dacc = (unsigned long long*)d_ws;
    int* conv = (int*)(dacc + 8);
    float* R1 = (float*)((char*)d_ws + 4096);
    float* R2 = R1 + BUF;
    float* R3 = R2 + BUF;
    float* E  = (float*)d_out;     // k f32 -> vthl plane -> final out

    const float scale = 0.35355339059327373f;     // 64^-0.25

    // 1. xnhl = pack(LN(x)) -> R2
    ln1024_pack_kernel<<<NROWS, 256, 0, stream>>>(x, lna, (unsigned*)R2);

    // 2. q,k,v GEMMs (bf16 hi/lo 3-term MFMA; k lands in d_out temporarily)
    dim3 gg(NROWS / 128, DIMS / 128);
    gemm_hl_kernel<<<gg, 256, 0, stream>>>((const unsigned*)R2, Wq, bq, R1, scale, 1);
    gemm_hl_kernel<<<gg, 256, 0, stream>>>((const unsigned*)R2, Wk, bq, E,  scale, 0);
    gemm_hl_kernel<<<gg, 256, 0, stream>>>((const unsigned*)R2, Wv, bv, R3, 1.0f, 1);

    // 3. per-head LN on q (R1), k (E)
    headln_kernel<<<NUNITS / 4, 256, 0, stream>>>(R1, E, lnb);

    // 4. kp plane (xnhl dead): E -> R2 ; vt plane (k dead): R3 -> E
    proj64_khl_kernel<<<NUNITS / 64, 256, 0, stream>>>(E, lkw, lkb, lnb, (unsigned*)R2);
    proj64_vthl_kernel<<<NUNITS / 64, 256, 0, stream>>>(R3, lvw, lvb, (unsigned*)E);

    // 5. control init
    init_ctrl_kernel<<<1, 64, 0, stream>>>(dacc, conv);

    const unsigned* KHL = (const unsigned*)R2;
    const unsigned* VTHL = (const unsigned*)E;

    // 6. it 0: o0 -> R3 (v f32 dead)
    attn_mfma_kernel<0, 0><<<512 * 8, 256, 0, stream>>>(R1, KHL, VTHL, R3, lqw, lqb, lnb, dacc, conv);
    // 7. qacc += scr(o0)
    scatter_add_kernel<<<NROWS * DIMS / 4 / 256, 256, 0, stream>>>(R1, R3);
    // 8. it 1: o1 -> R3 in place, fused per-window diff vs o0
    attn_mfma_kernel<1, 0><<<512 * 8, 256, 0, stream>>>(R1, KHL, VTHL, R3, lqw, lqb, lnb, dacc, conv);
    // 9. conv flags
    conv_from_acc_kernel<<<1, 64, 0, stream>>>(dacc, conv);
    // 10. qacc += scr(o1)
    scatter_add_kernel<<<NROWS * DIMS / 4 / 256, 256, 0, stream>>>(R1, R3);
    // 11. it 2: o2 -> R3, skipped for converged windows (keeps o1)
    attn_mfma_kernel<0, 1><<<512 * 8, 256, 0, stream>>>(R1, KHL, VTHL, R3, lqw, lqb, lnb, dacc, conv);

    // 12. preout_hl = pack(unscramble(R3)) -> R2 (khl dead)
    unscramble_pack_kernel<<<NROWS * DIMS / 4 / 256, 256, 0, stream>>>(R3, (unsigned*)R2);
    // 13. out = preout @ Wo^T + bo -> d_out (vthl dead)
    gemm_hl_kernel<<<gg, 256, 0, stream>>>((const unsigned*)R2, Wo, bo, (float*)d_out, 1.0f, 1);
}

// Round 6
// 1134.426 us; speedup vs baseline: 4.7563x; 1.5782x over previous
//
#include <hip/hip_runtime.h>
#include <math.h>

// Problem constants (from reference)
#define DIMS   1024
#define NHEAD  16
#define HD     64
#define WIN    512
#define CTX    4096
#define NBATCH 4
#define NROWS  (NBATCH*CTX)        // 16384 total sequence rows
#define NUNITS (NROWS*NHEAD)       // 262144 (row,head) units
#define LNEPS  1e-5f
#define FIXSCALE 16777216.0        // 2^24 fixed-point for deterministic diff

typedef __attribute__((ext_vector_type(8))) short bf16x8;   // 8 bf16 (4 VGPR)
typedef __attribute__((ext_vector_type(4))) float f32x4;    // MFMA C/D

__device__ __forceinline__ float4 ld4(const float* p) { return *reinterpret_cast<const float4*>(p); }
__device__ __forceinline__ void st4(float* p, float4 v) { *reinterpret_cast<float4*>(p) = v; }

__device__ __forceinline__ float wave_sum64(float v) {
#pragma unroll
    for (int off = 32; off; off >>= 1) v += __shfl_xor(v, off, 64);
    return v;
}
__device__ __forceinline__ float grp16_sum(float v) {
    v += __shfl_xor(v, 1, 64);
    v += __shfl_xor(v, 2, 64);
    v += __shfl_xor(v, 4, 64);
    v += __shfl_xor(v, 8, 64);
    return v;
}

// round-to-nearest-even bf16 of x, packed split: (hi<<16)|lo with hi+lo ~= x (err ~2^-17)
__device__ __forceinline__ unsigned bf16_rn_bits(float x) {
    unsigned u = __float_as_uint(x);
    return (u + 0x7fffu + ((u >> 16) & 1u)) >> 16;
}
__device__ __forceinline__ unsigned pack_hl(float x) {
    unsigned h = bf16_rn_bits(x);
    float hf = __uint_as_float(h << 16);
    unsigned l = bf16_rn_bits(x - hf);
    return (h << 16) | (l & 0xffffu);
}

// v_cvt_pk_bf16_f32: D[15:0]=bf16(a), D[31:16]=bf16(b)  (T12 recipe)
__device__ __forceinline__ unsigned cvtpk_bf16(float a, float b) {
    unsigned r;
    asm volatile("v_cvt_pk_bf16_f32 %0, %1, %2" : "=v"(r) : "v"(a), "v"(b));
    return r;
}
// split pair (a,b) into hi-word and lo-word (frag-word layout: short0=a, short1=b)
__device__ __forceinline__ void split_pair(float a, float b, unsigned& hw, unsigned& lw) {
    hw = cvtpk_bf16(a, b);
    float ha = __uint_as_float(hw << 16);
    float hb = __uint_as_float(hw & 0xffff0000u);
    lw = cvtpk_bf16(a - ha, b - hb);
}

// XOR-swizzled byte offset into a [rows][64] short LDS plane (stride 128 B)
__device__ __forceinline__ int swzo(int row, int kbyte) {
    return ((row << 7) + kbyte) ^ ((row & 7) << 4);
}

// -------- LayerNorm over D=1024 (row-wise), PACKED hi/lo output --------------
__global__ __launch_bounds__(256)
void ln1024_pack_kernel(const float* __restrict__ x, const float* __restrict__ w,
                        unsigned* __restrict__ outp) {
    int r = blockIdx.x;
    int tid = threadIdx.x;
    const float* xr = x + (size_t)r * DIMS;
    float4 v = ld4(xr + (tid << 2));
    __shared__ float red[8];
    float s = wave_sum64(v.x + v.y + v.z + v.w);
    int wv = tid >> 6, lane = tid & 63;
    if (lane == 0) red[wv] = s;
    __syncthreads();
    float mean = (red[0] + red[1] + red[2] + red[3]) * (1.0f / DIMS);
    float dx = v.x - mean, dy = v.y - mean, dz = v.z - mean, dw = v.w - mean;
    float ss = wave_sum64(dx*dx + dy*dy + dz*dz + dw*dw);
    if (lane == 0) red[4 + wv] = ss;
    __syncthreads();
    float inv = rsqrtf((red[4] + red[5] + red[6] + red[7]) * (1.0f / DIMS) + LNEPS);
    float4 wv4 = ld4(w + (tid << 2));
    uint4 pk;
    pk.x = pack_hl(dx * inv * wv4.x);
    pk.y = pack_hl(dy * inv * wv4.y);
    pk.z = pack_hl(dz * inv * wv4.z);
    pk.w = pack_hl(dw * inv * wv4.w);
    *reinterpret_cast<uint4*>(outp + (size_t)r * DIMS + (tid << 2)) = pk;
}

// -------- bf16 hi/lo 3-term MFMA GEMM ----------------------------------------
__global__ __launch_bounds__(256, 2)
void gemm_hl_kernel(const unsigned* __restrict__ Ahl, const float* __restrict__ W,
                    const float* __restrict__ bias, float* __restrict__ Cm,
                    float alpha, int has_bias) {
    __shared__ short Ah[128 * 64], Al[128 * 64], Wh[128 * 64], Wl[128 * 64]; // 64 KiB
    int tid = threadIdx.x;
    int wid = tid >> 6, lane = tid & 63;
    int wm = (wid >> 1) << 6, wn = (wid & 1) << 6;
    int g4 = lane >> 4, l16 = lane & 15;
    int m0 = blockIdx.x << 7, n0 = blockIdx.y << 7;

    f32x4 acc[4][4] = {};

    int orow[4], okb[4];
#pragma unroll
    for (int j = 0; j < 4; ++j) {
        int oc = tid + (j << 8);
        orow[j] = oc >> 3;
        okb[j] = (oc & 7) << 4;
    }

    for (int k0 = 0; k0 < 1024; k0 += 64) {
        uint4 a0[4], a1[4];
        float4 w0[4], w1[4];
#pragma unroll
        for (int j = 0; j < 4; ++j) {
            const unsigned* ap = Ahl + (size_t)(m0 + orow[j]) * 1024 + k0 + (okb[j] >> 1);
            a0[j] = *reinterpret_cast<const uint4*>(ap);
            a1[j] = *reinterpret_cast<const uint4*>(ap + 4);
            const float* wp = W + (size_t)(n0 + orow[j]) * 1024 + k0 + (okb[j] >> 1);
            w0[j] = *reinterpret_cast<const float4*>(wp);
            w1[j] = *reinterpret_cast<const float4*>(wp + 4);
        }
        __syncthreads();
#pragma unroll
        for (int j = 0; j < 4; ++j) {
            int off = swzo(orow[j], okb[j]);
            uint4 hi, lo;
            hi.x = __byte_perm(a0[j].x, a0[j].y, 0x7632);
            hi.y = __byte_perm(a0[j].z, a0[j].w, 0x7632);
            hi.z = __byte_perm(a1[j].x, a1[j].y, 0x7632);
            hi.w = __byte_perm(a1[j].z, a1[j].w, 0x7632);
            lo.x = __byte_perm(a0[j].x, a0[j].y, 0x5410);
            lo.y = __byte_perm(a0[j].z, a0[j].w, 0x5410);
            lo.z = __byte_perm(a1[j].x, a1[j].y, 0x5410);
            lo.w = __byte_perm(a1[j].z, a1[j].w, 0x5410);
            *reinterpret_cast<uint4*>(reinterpret_cast<char*>(Ah) + off) = hi;
            *reinterpret_cast<uint4*>(reinterpret_cast<char*>(Al) + off) = lo;

            float xs[8];
            *reinterpret_cast<float4*>(&xs[0]) = w0[j];
            *reinterpret_cast<float4*>(&xs[4]) = w1[j];
            uint4 hw4, lw4;
            unsigned* hwp = &hw4.x;
            unsigned* lwp = &lw4.x;
#pragma unroll
            for (int p = 0; p < 4; ++p) {
                unsigned u0 = __float_as_uint(xs[2*p]);
                unsigned u1 = __float_as_uint(xs[2*p + 1]);
                unsigned h0 = (u0 + 0x8000u) >> 16;
                unsigned h1 = (u1 + 0x8000u) >> 16;
                float l0 = xs[2*p]     - __uint_as_float(h0 << 16);
                float l1 = xs[2*p + 1] - __uint_as_float(h1 << 16);
                unsigned lb0 = (__float_as_uint(l0) + 0x8000u) >> 16;
                unsigned lb1 = (__float_as_uint(l1) + 0x8000u) >> 16;
                hwp[p] = h0 | (h1 << 16);
                lwp[p] = lb0 | (lb1 << 16);
            }
            *reinterpret_cast<uint4*>(reinterpret_cast<char*>(Wh) + off) = hw4;
            *reinterpret_cast<uint4*>(reinterpret_cast<char*>(Wl) + off) = lw4;
        }
        __syncthreads();

#pragma unroll
        for (int kk = 0; kk < 2; ++kk) {
            bf16x8 afh[4], afl[4], wfh[4], wfl[4];
#pragma unroll
            for (int mt = 0; mt < 4; ++mt) {
                int row = wm + (mt << 4) + l16;
                int off = ((row << 7) + (kk << 6) + (g4 << 4)) ^ ((row & 7) << 4);
                afh[mt] = *reinterpret_cast<const bf16x8*>(reinterpret_cast<const char*>(Ah) + off);
                afl[mt] = *reinterpret_cast<const bf16x8*>(reinterpret_cast<const char*>(Al) + off);
            }
#pragma unroll
            for (int nt = 0; nt < 4; ++nt) {
                int row = wn + (nt << 4) + l16;
                int off = ((row << 7) + (kk << 6) + (g4 << 4)) ^ ((row & 7) << 4);
                wfh[nt] = *reinterpret_cast<const bf16x8*>(reinterpret_cast<const char*>(Wh) + off);
                wfl[nt] = *reinterpret_cast<const bf16x8*>(reinterpret_cast<const char*>(Wl) + off);
            }
#pragma unroll
            for (int mt = 0; mt < 4; ++mt)
#pragma unroll
                for (int nt = 0; nt < 4; ++nt) {
                    acc[mt][nt] = __builtin_amdgcn_mfma_f32_16x16x32_bf16(afh[mt], wfh[nt], acc[mt][nt], 0, 0, 0);
                    acc[mt][nt] = __builtin_amdgcn_mfma_f32_16x16x32_bf16(afl[mt], wfh[nt], acc[mt][nt], 0, 0, 0);
                    acc[mt][nt] = __builtin_amdgcn_mfma_f32_16x16x32_bf16(afh[mt], wfl[nt], acc[mt][nt], 0, 0, 0);
                }
        }
    }

#pragma unroll
    for (int mt = 0; mt < 4; ++mt)
#pragma unroll
        for (int nt = 0; nt < 4; ++nt) {
            int col = n0 + wn + (nt << 4) + l16;
            float bb = has_bias ? bias[col] : 0.0f;
#pragma unroll
            for (int r = 0; r < 4; ++r) {
                int row = m0 + wm + (mt << 4) + (g4 << 2) + r;
                Cm[(size_t)row * DIMS + col] = alpha * (acc[mt][nt][r] + bb);
            }
        }
}

// -------- per-(row,head) LayerNorm over d=64, in place on q and k ------------
__global__ __launch_bounds__(256)
void headln_kernel(float* __restrict__ q, float* __restrict__ k,
                   const float* __restrict__ lnw) {
    int gw = (blockIdx.x << 2) + (threadIdx.x >> 6);
    int lane = threadIdx.x & 63;
    size_t idx = ((size_t)gw << 6) + lane;
    float wgt = lnw[lane];
    {
        float v = q[idx];
        float mean = wave_sum64(v) * (1.0f / 64.0f);
        float d = v - mean;
        float var = wave_sum64(d * d) * (1.0f / 64.0f);
        q[idx] = d * rsqrtf(var + LNEPS) * wgt;
    }
    {
        float v = k[idx];
        float mean = wave_sum64(v) * (1.0f / 64.0f);
        float d = v - mean;
        float var = wave_sum64(d * d) * (1.0f / 64.0f);
        k[idx] = d * rsqrtf(var + LNEPS) * wgt;
    }
}

// -------- kp projection + LN + hi/lo split -> packed K plane -----------------
__global__ __launch_bounds__(256)
void proj64_khl_kernel(const float* __restrict__ inp, const float* __restrict__ W,
                       const float* __restrict__ Wb, const float* __restrict__ lnw,
                       unsigned* __restrict__ plane) {
    int u0 = blockIdx.x << 6;
    __shared__ float As[64][68];
    __shared__ float Bs[64][68];
    int tid = threadIdx.x;
    for (int e = tid; e < 4096; e += 256) Bs[e & 63][e >> 6] = W[e];
    for (int e = tid; e < 1024; e += 256) {
        int row = e >> 4;
        int col = (e & 15) << 2;
        float4 v = ld4(inp + ((size_t)(u0 + row) << 6) + col);
        As[col + 0][row] = v.x; As[col + 1][row] = v.y;
        As[col + 2][row] = v.z; As[col + 3][row] = v.w;
    }
    __syncthreads();
    int tm = tid >> 4, tn = tid & 15;
    float acc[4][4] = {};
#pragma unroll
    for (int k = 0; k < 64; ++k) {
        float4 av = ld4(&As[k][tm << 2]);
        float4 bv = ld4(&Bs[k][tn << 2]);
        float aa[4] = {av.x, av.y, av.z, av.w};
        float bb[4] = {bv.x, bv.y, bv.z, bv.w};
#pragma unroll
        for (int mm = 0; mm < 4; ++mm)
#pragma unroll
            for (int nn = 0; nn < 4; ++nn)
                acc[mm][nn] = fmaf(aa[mm], bb[nn], acc[mm][nn]);
    }
    float bb4[4] = {Wb[(tn << 2) + 0], Wb[(tn << 2) + 1], Wb[(tn << 2) + 2], Wb[(tn << 2) + 3]};
    float lw4[4] = {lnw[(tn << 2) + 0], lnw[(tn << 2) + 1], lnw[(tn << 2) + 2], lnw[(tn << 2) + 3]};
#pragma unroll
    for (int mm = 0; mm < 4; ++mm) {
        float o0 = acc[mm][0] + bb4[0], o1 = acc[mm][1] + bb4[1];
        float o2 = acc[mm][2] + bb4[2], o3 = acc[mm][3] + bb4[3];
        float mean = grp16_sum(o0 + o1 + o2 + o3) * (1.0f / 64.0f);
        float d0 = o0 - mean, d1 = o1 - mean, d2 = o2 - mean, d3 = o3 - mean;
        float var = grp16_sum(d0*d0 + d1*d1 + d2*d2 + d3*d3) * (1.0f / 64.0f);
        float inv = rsqrtf(var + LNEPS);
        o0 = d0 * inv * lw4[0]; o1 = d1 * inv * lw4[1];
        o2 = d2 * inv * lw4[2]; o3 = d3 * inv * lw4[3];
        int u_p = u0 + (tm << 2) + mm;
        int r = u_p >> 4, h = u_p & 15;
        int s = r & 511;
        int ua = ((r >> 9) << 4) + h;
        size_t punit = (size_t)ua * 512 + s;
        uint4 pk;
        pk.x = pack_hl(o0); pk.y = pack_hl(o1); pk.z = pack_hl(o2); pk.w = pack_hl(o3);
        *reinterpret_cast<uint4*>(plane + (punit << 6) + (tn << 2)) = pk;
    }
}

// -------- vp projection + hi/lo split -> packed transposed V plane -----------
__global__ __launch_bounds__(256)
void proj64_vthl_kernel(const float* __restrict__ inp, const float* __restrict__ W,
                        const float* __restrict__ Wb, unsigned* __restrict__ plane) {
    int u0 = blockIdx.x << 6;
    __shared__ float As[64][68];
    __shared__ float Bs[64][68];
    int tid = threadIdx.x;
    for (int e = tid; e < 4096; e += 256) Bs[e & 63][e >> 6] = W[e];
    for (int e = tid; e < 1024; e += 256) {
        int row = e >> 4;
        int col = (e & 15) << 2;
        float4 v = ld4(inp + ((size_t)(u0 + row) << 6) + col);
        As[col + 0][row] = v.x; As[col + 1][row] = v.y;
        As[col + 2][row] = v.z; As[col + 3][row] = v.w;
    }
    __syncthreads();
    int tm = tid >> 4, tn = tid & 15;
    float acc[4][4] = {};
#pragma unroll
    for (int k = 0; k < 64; ++k) {
        float4 av = ld4(&As[k][tm << 2]);
        float4 bv = ld4(&Bs[k][tn << 2]);
        float aa[4] = {av.x, av.y, av.z, av.w};
        float bb[4] = {bv.x, bv.y, bv.z, bv.w};
#pragma unroll
        for (int mm = 0; mm < 4; ++mm)
#pragma unroll
            for (int nn = 0; nn < 4; ++nn)
                acc[mm][nn] = fmaf(aa[mm], bb[nn], acc[mm][nn]);
    }
    float bb4[4] = {Wb[(tn << 2) + 0], Wb[(tn << 2) + 1], Wb[(tn << 2) + 2], Wb[(tn << 2) + 3]};
#pragma unroll
    for (int mm = 0; mm < 4; ++mm) {
        int u_p = u0 + (tm << 2) + mm;
        int r = u_p >> 4, h = u_p & 15;
        int s = r & 511;
        int ua = ((r >> 9) << 4) + h;
        size_t base = ((size_t)(ua * 8 + (s >> 6)) << 12) + (s & 63);
#pragma unroll
        for (int nn = 0; nn < 4; ++nn) {
            int d = (tn << 2) + nn;
            plane[base + ((size_t)d << 6)] = pack_hl(acc[mm][nn] + bb4[nn]);
        }
    }
}

// -------- fused MFMA attention (phase-A MFMA + prefetch + cvt_pk) ------------
// blockIdx.x = trank*512 + u, t = 7-trank (long tiles dispatched first).
template<int DIFF, int USE_CONV>
__global__ __launch_bounds__(256)
void attn_mfma_kernel(const float* __restrict__ qacc, const unsigned* __restrict__ khl,
                      const unsigned* __restrict__ vthl, float* __restrict__ o_io,
                      const float* __restrict__ lqw, const float* __restrict__ lqb,
                      const float* __restrict__ lnw,
                      unsigned long long* __restrict__ diff_acc,
                      const int* __restrict__ conv) {
    __shared__ short kh[64][72], kl[64][72], vh[64][72], vl[64][72];   // 36864 B
    __shared__ float dred[4];

    int blk = blockIdx.x;
    int u = blk & 511;
    int t = 7 - (blk >> 9);
    int h = u & 15;
    int w = (u >> 4) & 7;
    int b = u >> 7;
    if (USE_CONV && conv[w]) return;
    int rowbase = b * CTX + w * WIN;
    int col0 = h * HD;
    int tid = threadIdx.x;
    int wv = tid >> 6;
    int lane = tid & 63;
    int g4 = lane >> 4;
    int qcol = lane & 15;
    int q_loc = (wv << 4) + qcol;
    int selhi = g4 >> 1;

    const unsigned* kbase = khl + (((size_t)u * 512) << 6);
    const unsigned* vbase = vthl + (((size_t)u * 8) << 12);

    // ---- prefetch chunk 0 (hides under phase A) ----
    uint4 kpre[4], vpre[4];
#pragma unroll
    for (int rr = 0; rr < 4; ++rr) {
        int row = (wv << 4) + (rr << 2) + g4;
        kpre[rr] = *reinterpret_cast<const uint4*>(kbase + ((size_t)row << 6) + (qcol << 2));
        vpre[rr] = *reinterpret_cast<const uint4*>(vbase + ((size_t)row << 6) + (qcol << 2));
    }

    // ---- phase A: qp^T = mfma(lqw, qacc^T), + bias, LN, -> Q frags ----
    // stage lqw hi/lo into kh/kl (row = output dim n, col = k)
#pragma unroll
    for (int rr = 0; rr < 4; ++rr) {
        int row = (wv << 4) + (rr << 2) + g4;
        float4 v = ld4(lqw + (row << 6) + (qcol << 2));
        unsigned h0, l0, h1, l1;
        split_pair(v.x, v.y, h0, l0);
        split_pair(v.z, v.w, h1, l1);
        *reinterpret_cast<uint2*>(&kh[row][qcol << 2]) = make_uint2(h0, h1);
        *reinterpret_cast<uint2*>(&kl[row][qcol << 2]) = make_uint2(l0, l1);
    }

    // B-frag from qacc (global): B[k][col=q], lane supplies col=qcol, k-slice g4*8
    bf16x8 bqh[2], bql[2];
    {
        const float* qrow = qacc + (size_t)(rowbase + (t << 6) + q_loc) * DIMS + col0;
#pragma unroll
        for (int kb = 0; kb < 2; ++kb) {
            float4 x0 = ld4(qrow + (kb << 5) + (g4 << 3));
            float4 x1 = ld4(qrow + (kb << 5) + (g4 << 3) + 4);
            unsigned hws[4], lws[4];
            split_pair(x0.x, x0.y, hws[0], lws[0]);
            split_pair(x0.z, x0.w, hws[1], lws[1]);
            split_pair(x1.x, x1.y, hws[2], lws[2]);
            split_pair(x1.z, x1.w, hws[3], lws[3]);
#pragma unroll
            for (int p2 = 0; p2 < 4; ++p2) {
                reinterpret_cast<unsigned*>(&bqh[kb])[p2] = hws[p2];
                reinterpret_cast<unsigned*>(&bql[kb])[p2] = lws[p2];
            }
        }
    }
    __syncthreads();   // lqw staged

    f32x4 qpa[4] = {{0,0,0,0},{0,0,0,0},{0,0,0,0},{0,0,0,0}};
    __builtin_amdgcn_s_setprio(1);
#pragma unroll
    for (int jt = 0; jt < 4; ++jt) {
        int arow = (jt << 4) + qcol;
#pragma unroll
        for (int kb = 0; kb < 2; ++kb) {
            bf16x8 ah = *reinterpret_cast<const bf16x8*>(&kh[arow][(kb << 5) + (g4 << 3)]);
            bf16x8 al = *reinterpret_cast<const bf16x8*>(&kl[arow][(kb << 5) + (g4 << 3)]);
            qpa[jt] = __builtin_amdgcn_mfma_f32_16x16x32_bf16(ah, bqh[kb], qpa[jt], 0, 0, 0);
            qpa[jt] = __builtin_amdgcn_mfma_f32_16x16x32_bf16(al, bqh[kb], qpa[jt], 0, 0, 0);
            qpa[jt] = __builtin_amdgcn_mfma_f32_16x16x32_bf16(ah, bql[kb], qpa[jt], 0, 0, 0);
        }
    }
    __builtin_amdgcn_s_setprio(0);

    // bias + LN over the 64 d' per q (lane's d' = jt*16 + g4*4 + r)
    float vals[16];
    float s1 = 0.0f;
#pragma unroll
    for (int jt = 0; jt < 4; ++jt) {
        float4 b4 = ld4(lqb + (jt << 4) + (g4 << 2));
        const float* b4p = reinterpret_cast<const float*>(&b4);
#pragma unroll
        for (int r = 0; r < 4; ++r) {
            float v = qpa[jt][r] + b4p[r];
            vals[(jt << 2) + r] = v;
            s1 += v;
        }
    }
    s1 += __shfl_xor(s1, 16, 64);
    s1 += __shfl_xor(s1, 32, 64);
    float mean = s1 * (1.0f / 64.0f);
    float s2 = 0.0f;
#pragma unroll
    for (int e = 0; e < 16; ++e) { float d = vals[e] - mean; vals[e] = d; s2 += d * d; }
    s2 += __shfl_xor(s2, 16, 64);
    s2 += __shfl_xor(s2, 32, 64);
    float inv = rsqrtf(s2 * (1.0f / 64.0f) + LNEPS);
#pragma unroll
    for (int jt = 0; jt < 4; ++jt) {
        float4 w4 = ld4(lnw + (jt << 4) + (g4 << 2));
        const float* w4p = reinterpret_cast<const float*>(&w4);
#pragma unroll
        for (int r = 0; r < 4; ++r) vals[(jt << 2) + r] *= inv * w4p[r];
    }

    // pack pairs + shfl-redistribute -> Q B-frags (verified P^T pattern)
    bf16x8 qfh[2], qfl[2];
    {
        unsigned hw[8], lw[8];
#pragma unroll
        for (int jt = 0; jt < 4; ++jt) {
            split_pair(vals[(jt << 2) + 0], vals[(jt << 2) + 1], hw[(jt << 1) + 0], lw[(jt << 1) + 0]);
            split_pair(vals[(jt << 2) + 2], vals[(jt << 2) + 3], hw[(jt << 1) + 1], lw[(jt << 1) + 1]);
        }
#pragma unroll
        for (int kb = 0; kb < 2; ++kb)
#pragma unroll
            for (int ip = 0; ip < 4; ++ip) {
                int srcl = (((g4 & 1) << 1) + (ip >> 1)) * 16 + qcol;
                unsigned hA = __shfl(hw[(kb << 2) + (ip & 1)], srcl, 64);
                unsigned hB = __shfl(hw[(kb << 2) + 2 + (ip & 1)], srcl, 64);
                unsigned lA = __shfl(lw[(kb << 2) + (ip & 1)], srcl, 64);
                unsigned lB = __shfl(lw[(kb << 2) + 2 + (ip & 1)], srcl, 64);
                reinterpret_cast<unsigned*>(&qfh[kb])[ip] = selhi ? hB : hA;
                reinterpret_cast<unsigned*>(&qfl[kb])[ip] = selhi ? lB : lA;
            }
    }
    __syncthreads();   // phase-A LDS reads done; planes free for K/V

    // ---- flash loop ----
    float m_r = -INFINITY, l_r = 0.0f;
    f32x4 oacc[4] = {{0,0,0,0},{0,0,0,0},{0,0,0,0},{0,0,0,0}};

    for (int c = 0; c <= t; ++c) {
        // write prefetched chunk to LDS (split hi/lo)
#pragma unroll
        for (int rr = 0; rr < 4; ++rr) {
            int row = (wv << 4) + (rr << 2) + g4;
            uint4 pk = kpre[rr];
            unsigned* khp = reinterpret_cast<unsigned*>(&kh[row][qcol << 2]);
            khp[0] = __byte_perm(pk.x, pk.y, 0x7632);
            khp[1] = __byte_perm(pk.z, pk.w, 0x7632);
            unsigned* klp = reinterpret_cast<unsigned*>(&kl[row][qcol << 2]);
            klp[0] = __byte_perm(pk.x, pk.y, 0x5410);
            klp[1] = __byte_perm(pk.z, pk.w, 0x5410);
            uint4 pv = vpre[rr];
            unsigned* vhp = reinterpret_cast<unsigned*>(&vh[row][qcol << 2]);
            vhp[0] = __byte_perm(pv.x, pv.y, 0x7632);
            vhp[1] = __byte_perm(pv.z, pv.w, 0x7632);
            unsigned* vlp = reinterpret_cast<unsigned*>(&vl[row][qcol << 2]);
            vlp[0] = __byte_perm(pv.x, pv.y, 0x5410);
            vlp[1] = __byte_perm(pv.z, pv.w, 0x5410);
        }
        // issue next chunk's loads early (T14)
        if (c < t) {
            const unsigned* ksrc = kbase + (((size_t)(c + 1) * 64) << 6);
            const unsigned* vsrc = vbase + (((size_t)(c + 1)) << 12);
#pragma unroll
            for (int rr = 0; rr < 4; ++rr) {
                int row = (wv << 4) + (rr << 2) + g4;
                kpre[rr] = *reinterpret_cast<const uint4*>(ksrc + ((size_t)row << 6) + (qcol << 2));
                vpre[rr] = *reinterpret_cast<const uint4*>(vsrc + ((size_t)row << 6) + (qcol << 2));
            }
        }
        __syncthreads();

        // S^T = K * Q^T (3-term hi/lo)
        f32x4 sacc[4] = {{0,0,0,0},{0,0,0,0},{0,0,0,0},{0,0,0,0}};
        __builtin_amdgcn_s_setprio(1);
#pragma unroll
        for (int jt = 0; jt < 4; ++jt) {
            int jrow = (jt << 4) + qcol;
#pragma unroll
            for (int kb = 0; kb < 2; ++kb) {
                bf16x8 ah = *reinterpret_cast<const bf16x8*>(&kh[jrow][(kb << 5) + (g4 << 3)]);
                bf16x8 al = *reinterpret_cast<const bf16x8*>(&kl[jrow][(kb << 5) + (g4 << 3)]);
                sacc[jt] = __builtin_amdgcn_mfma_f32_16x16x32_bf16(ah, qfh[kb], sacc[jt], 0, 0, 0);
                sacc[jt] = __builtin_amdgcn_mfma_f32_16x16x32_bf16(al, qfh[kb], sacc[jt], 0, 0, 0);
                sacc[jt] = __builtin_amdgcn_mfma_f32_16x16x32_bf16(ah, qfl[kb], sacc[jt], 0, 0, 0);
            }
        }
        __builtin_amdgcn_s_setprio(0);

        // online softmax (lane owns query q_loc; 16 j-values, 4-group replicated)
        float sv[16];
        float mx = -3.0e38f;
#pragma unroll
        for (int jt = 0; jt < 4; ++jt)
#pragma unroll
            for (int r = 0; r < 4; ++r) {
                float s = sacc[jt][r] * 0.125f;
                if (c == t) {
                    int j_loc = (jt << 4) + (g4 << 2) + r;
                    if (j_loc > q_loc) s = -3.0e38f;
                }
                sv[(jt << 2) + r] = s;
                mx = fmaxf(mx, s);
            }
        mx = fmaxf(mx, __shfl_xor(mx, 16, 64));
        mx = fmaxf(mx, __shfl_xor(mx, 32, 64));
        float mnew = fmaxf(m_r, mx);
        float ps = 0.0f;
#pragma unroll
        for (int e = 0; e < 16; ++e) {
            float p = __expf(sv[e] - mnew);
            sv[e] = p;
            ps += p;
        }
        ps += __shfl_xor(ps, 16, 64);
        ps += __shfl_xor(ps, 32, 64);
        float ef = __expf(m_r - mnew);
        l_r = l_r * ef + ps;
        m_r = mnew;
#pragma unroll
        for (int dt = 0; dt < 4; ++dt) oacc[dt] *= ef;

        // pack P pairs
        unsigned hwp[8], lwp[8];
#pragma unroll
        for (int jt = 0; jt < 4; ++jt) {
            split_pair(sv[(jt << 2) + 0], sv[(jt << 2) + 1], hwp[(jt << 1) + 0], lwp[(jt << 1) + 0]);
            split_pair(sv[(jt << 2) + 2], sv[(jt << 2) + 3], hwp[(jt << 1) + 1], lwp[(jt << 1) + 1]);
        }

        // O^T += V^T * P^T (P B-frags assembled via shfl)
        __builtin_amdgcn_s_setprio(1);
#pragma unroll
        for (int kb2 = 0; kb2 < 2; ++kb2) {
            bf16x8 ph, pl;
#pragma unroll
            for (int ip = 0; ip < 4; ++ip) {
                int srcl = (((g4 & 1) << 1) + (ip >> 1)) * 16 + qcol;
                unsigned hA = __shfl(hwp[(kb2 << 2) + (ip & 1)], srcl, 64);
                unsigned hB = __shfl(hwp[(kb2 << 2) + 2 + (ip & 1)], srcl, 64);
                unsigned lA = __shfl(lwp[(kb2 << 2) + (ip & 1)], srcl, 64);
                unsigned lB = __shfl(lwp[(kb2 << 2) + 2 + (ip & 1)], srcl, 64);
                reinterpret_cast<unsigned*>(&ph)[ip] = selhi ? hB : hA;
                reinterpret_cast<unsigned*>(&pl)[ip] = selhi ? lB : lA;
            }
#pragma unroll
            for (int dt = 0; dt < 4; ++dt) {
                int drow = (dt << 4) + qcol;
                bf16x8 ah = *reinterpret_cast<const bf16x8*>(&vh[drow][(kb2 << 5) + (g4 << 3)]);
                bf16x8 al = *reinterpret_cast<const bf16x8*>(&vl[drow][(kb2 << 5) + (g4 << 3)]);
                oacc[dt] = __builtin_amdgcn_mfma_f32_16x16x32_bf16(ah, ph, oacc[dt], 0, 0, 0);
                oacc[dt] = __builtin_amdgcn_mfma_f32_16x16x32_bf16(al, ph, oacc[dt], 0, 0, 0);
                oacc[dt] = __builtin_amdgcn_mfma_f32_16x16x32_bf16(ah, pl, oacc[dt], 0, 0, 0);
            }
        }
        __builtin_amdgcn_s_setprio(0);
        __syncthreads();   // all LDS reads done before next chunk's staging
    }

    // ---- epilogue ----
    float invl = 1.0f / l_r;
    float dsum = 0.0f;
    float* orow = o_io + (size_t)(rowbase + (t << 6) + q_loc) * DIMS + col0;
#pragma unroll
    for (int dt = 0; dt < 4; ++dt) {
        float4 ov = make_float4(oacc[dt][0] * invl, oacc[dt][1] * invl,
                                oacc[dt][2] * invl, oacc[dt][3] * invl);
        float* addr = orow + (dt << 4) + (g4 << 2);
        if (DIFF) {
            float4 pv4 = ld4(addr);
            dsum += fabsf(ov.x - pv4.x) + fabsf(ov.y - pv4.y)
                  + fabsf(ov.z - pv4.z) + fabsf(ov.w - pv4.w);
        }
        st4(addr, ov);
    }
    if (DIFF) {
        float s = wave_sum64(dsum);
        if (lane == 0) dred[wv] = s;
        __syncthreads();
        if (tid == 0) {
            double tot = (double)(dred[0] + dred[1] + dred[2] + dred[3]);
            unsigned long long q = (unsigned long long)(tot * FIXSCALE + 0.5);
            atomicAdd(&diff_acc[w], q);
        }
    }
}

// -------- qacc[u,:] += scramble(o)[u,:]  (torch q_cur += iter_out) -----------
__global__ __launch_bounds__(256)
void scatter_add_kernel(float* __restrict__ qacc, const float* __restrict__ o) {
    size_t gid = (size_t)blockIdx.x * 256 + threadIdx.x;
    size_t flat = gid << 2;
    int uu = (int)(flat >> 6);
    int col = (int)(flat & 63);
    int r = uu >> 4, h = uu & 15;
    int s = r & 511;
    int rb = r - s;
    size_t src = ((size_t)(rb + h * 32 + (s >> 4)) << 10)
               + (size_t)((s & 15) << 6) + col;
    float4 a = ld4(qacc + flat);
    float4 bv = ld4(o + src);
    st4(qacc + flat, make_float4(a.x + bv.x, a.y + bv.y, a.z + bv.z, a.w + bv.w));
}

__global__ void init_ctrl_kernel(unsigned long long* __restrict__ dacc,
                                 int* __restrict__ conv) {
    int i = threadIdx.x;
    if (i < 8) { dacc[i] = 0ULL; conv[i] = 0; }
}

__global__ void conv_from_acc_kernel(const unsigned long long* __restrict__ dacc,
                                     int* __restrict__ conv) {
    int w = threadIdx.x;
    if (w < 8) {
        float mean = (float)((double)dacc[w] * (1.0 / (FIXSCALE * 2097152.0)));
        conv[w] = (mean < 0.01f + 0.1f * mean) ? 1 : 0;
    }
}

// -------- unscramble src into packed-hl preout [B,S,DIMS] --------------------
__global__ __launch_bounds__(256)
void unscramble_pack_kernel(const float* __restrict__ src, unsigned* __restrict__ outp) {
    size_t gid = (size_t)blockIdx.x * 256 + threadIdx.x;
    size_t flat = gid << 2;
    int r = (int)(flat >> 10);
    int e = (int)(flat & 1023);
    int h2 = e >> 6, d2 = e & 63;
    int s2 = r & 511;
    int rb = r - s2;
    size_t sidx = ((size_t)(rb + h2 * 32 + (s2 >> 4)) << 10) + (size_t)((s2 & 15) << 6) + d2;
    float4 v = ld4(src + sidx);
    uint4 pk;
    pk.x = pack_hl(v.x); pk.y = pack_hl(v.y); pk.z = pack_hl(v.z); pk.w = pack_hl(v.w);
    *reinterpret_cast<uint4*>(outp + flat) = pk;
}

extern "C" void kernel_launch(void* const* d_in, const int* in_sizes, int n_in,
                              void* d_out, int out_size, void* d_ws, size_t ws_size,
                              hipStream_t stream) {
    (void)in_sizes; (void)n_in; (void)out_size; (void)ws_size;
    const float* x   = (const float*)d_in[0];
    const float* Wq  = (const float*)d_in[1];
    const float* bq  = (const float*)d_in[2];
    const float* Wk  = (const float*)d_in[3];
    const float* Wv  = (const float*)d_in[4];
    const float* bv  = (const float*)d_in[5];
    const float* Wo  = (const float*)d_in[6];
    const float* bo  = (const float*)d_in[7];
    const float* lna = (const float*)d_in[8];
    const float* lnb = (const float*)d_in[9];
    const float* lqw = (const float*)d_in[10];
    const float* lqb = (const float*)d_in[11];
    const float* lkw = (const float*)d_in[12];
    const float* lkb = (const float*)d_in[13];
    const float* lvw = (const float*)d_in[14];
    const float* lvb = (const float*)d_in[15];

    // ws: [4 KiB ctrl][R1 qacc][R2 xnhl->khl->preout_hl][R3 v->o] = 192 MiB + 4 KiB
    const size_t BUF = (size_t)NROWS * DIMS;      // 16M elements
    unsigned long long* dacc = (unsigned long long*)d_ws;
    int* conv = (int*)(dacc + 8);
    float* R1 = (float*)((char*)d_ws + 4096);
    float* R2 = R1 + BUF;
    float* R3 = R2 + BUF;
    float* E  = (float*)d_out;     // k f32 -> vthl plane -> final out

    const float scale = 0.35355339059327373f;     // 64^-0.25

    // 1. xnhl = pack(LN(x)) -> R2
    ln1024_pack_kernel<<<NROWS, 256, 0, stream>>>(x, lna, (unsigned*)R2);

    // 2. q,k,v GEMMs (bf16 hi/lo 3-term MFMA; k lands in d_out temporarily)
    dim3 gg(NROWS / 128, DIMS / 128);
    gemm_hl_kernel<<<gg, 256, 0, stream>>>((const unsigned*)R2, Wq, bq, R1, scale, 1);
    gemm_hl_kernel<<<gg, 256, 0, stream>>>((const unsigned*)R2, Wk, bq, E,  scale, 0);
    gemm_hl_kernel<<<gg, 256, 0, stream>>>((const unsigned*)R2, Wv, bv, R3, 1.0f, 1);

    // 3. per-head LN on q (R1), k (E)
    headln_kernel<<<NUNITS / 4, 256, 0, stream>>>(R1, E, lnb);

    // 4. kp plane (xnhl dead): E -> R2 ; vt plane (k dead): R3 -> E
    proj64_khl_kernel<<<NUNITS / 64, 256, 0, stream>>>(E, lkw, lkb, lnb, (unsigned*)R2);
    proj64_vthl_kernel<<<NUNITS / 64, 256, 0, stream>>>(R3, lvw, lvb, (unsigned*)E);

    // 5. control init
    init_ctrl_kernel<<<1, 64, 0, stream>>>(dacc, conv);

    const unsigned* KHL = (const unsigned*)R2;
    const unsigned* VTHL = (const unsigned*)E;

    // 6. it 0: o0 -> R3 (v f32 dead)
    attn_mfma_kernel<0, 0><<<512 * 8, 256, 0, stream>>>(R1, KHL, VTHL, R3, lqw, lqb, lnb, dacc, conv);
    // 7. qacc += scr(o0)
    scatter_add_kernel<<<NROWS * DIMS / 4 / 256, 256, 0, stream>>>(R1, R3);
    // 8. it 1: o1 -> R3 in place, fused per-window diff vs o0
    attn_mfma_kernel<1, 0><<<512 * 8, 256, 0, stream>>>(R1, KHL, VTHL, R3, lqw, lqb, lnb, dacc, conv);
    // 9. conv flags
    conv_from_acc_kernel<<<1, 64, 0, stream>>>(dacc, conv);
    // 10. qacc += scr(o1)
    scatter_add_kernel<<<NROWS * DIMS / 4 / 256, 256, 0, stream>>>(R1, R3);
    // 11. it 2: o2 -> R3, skipped for converged windows (keeps o1)
    attn_mfma_kernel<0, 1><<<512 * 8, 256, 0, stream>>>(R1, KHL, VTHL, R3, lqw, lqb, lnb, dacc, conv);

    // 12. preout_hl = pack(unscramble(R3)) -> R2 (khl dead)
    unscramble_pack_kernel<<<NROWS * DIMS / 4 / 256, 256, 0, stream>>>(R3, (unsigned*)R2);
    // 13. out = preout @ Wo^T + bo -> d_out (vthl dead)
    gemm_hl_kernel<<<gg, 256, 0, stream>>>((const unsigned*)R2, Wo, bo, (float*)d_out, 1.0f, 1);
}